// Round 1
// baseline (598.123 us; speedup 1.0000x reference)
//
#include <hip/hip_runtime.h>
#include <math.h>

#define EPSF 1e-9f
#define INV_SQRT128 0.08838834764831845f

// LDS swizzles (indices in float4 units)
#define XS2(r, kc) ((r) * 32 + ((kc) ^ (((r) >> 2) & 7)))   // kc < 32
#define WS2(c, kc) ((c) * 16 + ((kc) ^ (((c) >> 2) & 7)))   // kc < 16 (K-half)

// async global->LDS, 16B per lane, LDS dest = wave-uniform base + lane*16
__device__ __forceinline__ void gl_lds16(const void* g, void* l) {
    __builtin_amdgcn_global_load_lds((const __attribute__((address_space(1))) void*)g,
                                     (__attribute__((address_space(3))) void*)l, 16, 0, 0);
}

// ---------------- fused: q/k/v projections on RAW x (+ histogram role) ----------------
// 128 threads/block, 64 rows, 8x8 register tile. Round-8 change: LDS cut 48KB->25KB
// (raw-x K-quarter 8KB + W K-quarter 16KB), both staged async via global_load_lds
// with source-pre-swizzled addresses (linear LDS dest). Row normalization is folded
// into the epilogue: normalize(x)@Wcol = rn*(x@Wcol) + x_time*W127*(1-rn), so the
// MAC loop runs on raw x and the 64-VGPR register staging array is gone. Goal:
// occupancy 13.5% -> ~30% (latency-bound fix); MAC loop itself is unchanged.
__global__ void __launch_bounds__(128, 3)
k_qkv3(const float* __restrict__ x,
       const float* __restrict__ Wq, const float* __restrict__ bq,
       const float* __restrict__ Wk, const float* __restrict__ bk,
       const float* __restrict__ Wv, const float* __restrict__ bv,
       float* __restrict__ qn, float* __restrict__ kvout,
       const int* __restrict__ ei, int* __restrict__ counts,
       int NB, int N, int E) {
    if ((int)blockIdx.x >= NB) {   // histogram role
        int stride = ((int)gridDim.x - NB) * 128;
        for (int e = ((int)blockIdx.x - NB) * 128 + (int)threadIdx.x; e < E; e += stride)
            atomicAdd(&counts[ei[e]], 1);
        return;
    }

    __shared__ float4 xsq[64 * 8];    // 8 KB raw-x K-quarter (src-swizzled layout)
    __shared__ float4 wsq[128 * 8];   // 16 KB W K-quarter (src-swizzled layout)
    __shared__ float rns[64];         // per-row 1/max(|spatial|,eps)
    __shared__ float xtc[64];         // per-row x_time*(1-rn) correction factor

    int tid = threadIdx.x;            // 0..127
    int wv = tid >> 6;                // wave id
    int ln = tid & 63;
    int rg = tid >> 4;                // 8 row-groups x 8 rows
    int cg = tid & 15;                // 16 col-groups x 8 cols
    int base = blockIdx.x * 64;
    const float4* x4 = (const float4*)x;

    // prologue: per-row spatial-norm + time correction (2 threads per row)
    {
        int row2 = tid >> 1, half = tid & 1;
        int grow = min(base + row2, N - 1);
        const float4* xr = x4 + (size_t)grow * 32 + half * 16;
        float s = 0.f, tl = 0.f;
#pragma unroll
        for (int m = 0; m < 16; m++) {
            float4 t = xr[m];
            s += t.x * t.x + t.y * t.y + t.z * t.z + t.w * t.w;
            if (m == 15) tl = t.w;
        }
        if (half) s -= tl * tl;       // drop elem 127 (time) from spatial norm
        s += __shfl_xor(s, 1);
        if (half) {
            float rn = 1.f / fmaxf(sqrtf(s), EPSF);
            rns[row2] = rn;
            xtc[row2] = tl * (1.f - rn);
        }
    }

    const float* const Wks[3] = {Wq, Wk, Wv};
    const float* const bks[3] = {bq, bk, bv};
    bool istime = ((cg & 7) == 7);    // col cg*8+7 is this head's time coord
    int lr = ln >> 3;                 // lane's row offset within an 8-row stripe
    int lk = ln & 7;                  // lane's kc2

#pragma unroll
    for (int kind = 0; kind < 3; kind++) {
        const float4* W4 = (const float4*)Wks[kind];
        float acc[8][8];
#pragma unroll
        for (int i = 0; i < 8; i++)
#pragma unroll
            for (int j = 0; j < 8; j++) acc[i][j] = 0.f;

        for (int kp = 0; kp < 4; kp++) {
            __syncthreads();          // previous quarter fully consumed
            // stage raw-x quarter: LDS slot (row,kc2) <- x[row][kp*8 + (kc2 ^ (row>>3))]
#pragma unroll
            for (int i = 0; i < 4; i++) {
                int row = wv * 32 + i * 8 + lr;
                const float4* src = x4 + (size_t)min(base + row, N - 1) * 32
                                  + kp * 8 + (lk ^ ((wv * 4 + i) & 7));
                gl_lds16(src, xsq + wv * 256 + i * 64);
            }
            // stage W quarter: LDS slot (col,kc2) <- W[col][kp*8 + (kc2 ^ (col>>3 & 7))]
#pragma unroll
            for (int i = 0; i < 8; i++) {
                int col = wv * 64 + i * 8 + lr;
                const float4* src = W4 + (size_t)col * 32
                                  + kp * 8 + (lk ^ ((wv * 8 + i) & 7));
                gl_lds16(src, wsq + wv * 512 + i * 64);
            }
            asm volatile("s_waitcnt vmcnt(0)" ::: "memory");
            __syncthreads();
#pragma unroll
            for (int kc2 = 0; kc2 < 8; kc2++) {
                float4 xa[8], wb[8];
#pragma unroll
                for (int i = 0; i < 8; i++)
                    xa[i] = xsq[(rg * 8 + i) * 8 + (kc2 ^ rg)];
#pragma unroll
                for (int j = 0; j < 8; j++)
                    wb[j] = wsq[(cg * 8 + j) * 8 + (kc2 ^ (cg & 7))];
#pragma unroll
                for (int i = 0; i < 8; i++)
#pragma unroll
                    for (int j = 0; j < 8; j++) {
                        acc[i][j] = fmaf(xa[i].x, wb[j].x, acc[i][j]);
                        acc[i][j] = fmaf(xa[i].y, wb[j].y, acc[i][j]);
                        acc[i][j] = fmaf(xa[i].z, wb[j].z, acc[i][j]);
                        acc[i][j] = fmaf(xa[i].w, wb[j].w, acc[i][j]);
                    }
            }
        }

        // epilogue: normalize-correction + bias, per-(row,head) normalize for q/k
        float w127[8];
#pragma unroll
        for (int j = 0; j < 8; j++)
            w127[j] = Wks[kind][(size_t)(cg * 8 + j) * 128 + 127];
        float4 bb0 = ((const float4*)bks[kind])[cg * 2];
        float4 bb1 = ((const float4*)bks[kind])[cg * 2 + 1];
#pragma unroll
        for (int i = 0; i < 8; i++) {
            int r = rg * 8 + i;
            int row = base + r;
            float rn = rns[r];
            float tc = xtc[r];
            float c0 = fmaf(rn, acc[i][0], fmaf(tc, w127[0], bb0.x));
            float c1 = fmaf(rn, acc[i][1], fmaf(tc, w127[1], bb0.y));
            float c2 = fmaf(rn, acc[i][2], fmaf(tc, w127[2], bb0.z));
            float c3 = fmaf(rn, acc[i][3], fmaf(tc, w127[3], bb0.w));
            float c4 = fmaf(rn, acc[i][4], fmaf(tc, w127[4], bb1.x));
            float c5 = fmaf(rn, acc[i][5], fmaf(tc, w127[5], bb1.y));
            float c6 = fmaf(rn, acc[i][6], fmaf(tc, w127[6], bb1.z));
            float c7 = fmaf(rn, acc[i][7], fmaf(tc, w127[7], bb1.w));
            if (kind < 2) {
                float ss = c0 * c0 + c1 * c1 + c2 * c2 + c3 * c3 +
                           c4 * c4 + c5 * c5 + c6 * c6 + (istime ? 0.f : c7 * c7);
                // head = 8 consecutive lanes (same rg); sum over cg&7
                ss += __shfl_xor(ss, 1);
                ss += __shfl_xor(ss, 2);
                ss += __shfl_xor(ss, 4);
                float rh = 1.f / fmaxf(sqrtf(ss), EPSF);
                c0 *= rh; c1 *= rh; c2 *= rh; c3 *= rh;
                c4 *= rh; c5 *= rh; c6 *= rh;
                if (!istime) c7 *= rh;
                if (kind == 0) {
                    if (istime) c7 = -c7;       // fold uhg minus into q
                    c0 *= INV_SQRT128; c1 *= INV_SQRT128;
                    c2 *= INV_SQRT128; c3 *= INV_SQRT128;
                    c4 *= INV_SQRT128; c5 *= INV_SQRT128;
                    c6 *= INV_SQRT128; c7 *= INV_SQRT128;
                }
            }
            if (row < N) {
                float4 o0 = {c0, c1, c2, c3};
                float4 o1 = {c4, c5, c6, c7};
                float4* dst = (kind == 0)
                    ? (float4*)(qn + (size_t)row * 128)
                    : (float4*)(kvout + (size_t)row * 256 + (kind == 2 ? 128 : 0));
                dst[cg * 2] = o0;
                dst[cg * 2 + 1] = o1;
            }
        }
    }
}

// ---------------- CSR build (scan + fill) ----------------
__global__ void k_scan1(const int* __restrict__ counts, int* __restrict__ offs,
                        int* __restrict__ tsum, int N) {
    __shared__ int sd[256];
    int tile = blockIdx.x;
    int t = threadIdx.x;
    int i0 = tile * 1024 + t * 4;
    int v[4];
    int lsum = 0;
    for (int j = 0; j < 4; j++) {
        int idx = i0 + j;
        v[j] = (idx < N) ? counts[idx] : 0;
        lsum += v[j];
    }
    sd[t] = lsum;
    __syncthreads();
    for (int off = 1; off < 256; off <<= 1) {
        int val = sd[t];
        int add = (t >= off) ? sd[t - off] : 0;
        __syncthreads();
        sd[t] = val + add;
        __syncthreads();
    }
    int excl = (t == 0) ? 0 : sd[t - 1];
    if (t == 255) tsum[tile] = sd[255];
    int run = excl;
    for (int j = 0; j < 4; j++) {
        int idx = i0 + j;
        if (idx < N) offs[idx] = run;
        run += v[j];
    }
}

__global__ void k_scan2(int* __restrict__ tsum, int* __restrict__ offs, int T, int N) {
    if (threadIdx.x == 0) {
        int run = 0;
        for (int i = 0; i < T; i++) {
            int t = tsum[i];
            tsum[i] = run;
            run += t;
        }
        offs[N] = run;
    }
}

__global__ void k_scan3(int* __restrict__ offs, int* __restrict__ cursor,
                        const int* __restrict__ tsum, int N) {
    int i = blockIdx.x * blockDim.x + threadIdx.x;
    if (i < N) {
        int o = offs[i] + tsum[i >> 10];
        offs[i] = o;
        cursor[i] = o;
    }
}

// stores the COLUMN id in CSR order
__global__ void k_fill(const int* __restrict__ ei, int* __restrict__ cursor,
                       int* __restrict__ ccol, int E) {
    int stride = blockDim.x * gridDim.x;
    for (int e = blockIdx.x * blockDim.x + threadIdx.x; e < E; e += stride) {
        int r = ei[e];
        int p = atomicAdd(&cursor[r], 1);
        ccol[p] = ei[E + e];
    }
}

// ---------------- fused edge pass: scores + exp + aggregate (unnormalized) ----------------
// kv[n] = [k-row | v-row] (256B-local gather per edge). Unroll-2 for MLP.
__global__ void k_edge(const float* __restrict__ qn, const float* __restrict__ kv,
                       const int* __restrict__ offs, const int* __restrict__ ccol,
                       float* __restrict__ U, double* __restrict__ psum, int N) {
    int g = threadIdx.x >> 5;            // 8 groups of 32 lanes
    int l = threadIdx.x & 31;
    int head = l >> 4;
    int n = blockIdx.x * 8 + g;
    double esum = 0.0;
    if (n < N) {
        float4 q4 = ((const float4*)qn)[(size_t)n * 32 + l];
        int s0 = offs[n], s1 = offs[n + 1];
        float4 acc = {0.f, 0.f, 0.f, 0.f};
        const float4* kv4 = (const float4*)kv;
        int i = s0;
        for (; i + 2 <= s1; i += 2) {
            int c0 = ccol[i];
            int c1 = ccol[i + 1];
            float4 ka = kv4[(size_t)c0 * 64 + l];
            float4 kb = kv4[(size_t)c1 * 64 + l];
            float4 va = kv4[(size_t)c0 * 64 + 32 + l];
            float4 vb = kv4[(size_t)c1 * 64 + 32 + l];
            float p0 = q4.x * ka.x;
            p0 = fmaf(q4.y, ka.y, p0);
            p0 = fmaf(q4.z, ka.z, p0);
            p0 = fmaf(q4.w, ka.w, p0);
            float p1 = q4.x * kb.x;
            p1 = fmaf(q4.y, kb.y, p1);
            p1 = fmaf(q4.z, kb.z, p1);
            p1 = fmaf(q4.w, kb.w, p1);
            p0 += __shfl_xor(p0, 1);
            p1 += __shfl_xor(p1, 1);
            p0 += __shfl_xor(p0, 2);
            p1 += __shfl_xor(p1, 2);
            p0 += __shfl_xor(p0, 4);
            p1 += __shfl_xor(p1, 4);
            p0 += __shfl_xor(p0, 8);
            p1 += __shfl_xor(p1, 8);
            float e0 = expf(p0);
            float e1 = expf(p1);
            acc.x = fmaf(va.x, e0, acc.x);
            acc.y = fmaf(va.y, e0, acc.y);
            acc.z = fmaf(va.z, e0, acc.z);
            acc.w = fmaf(va.w, e0, acc.w);
            acc.x = fmaf(vb.x, e1, acc.x);
            acc.y = fmaf(vb.y, e1, acc.y);
            acc.z = fmaf(vb.z, e1, acc.z);
            acc.w = fmaf(vb.w, e1, acc.w);
            if ((l & 15) == 0) esum += (double)e0 + (double)e1;
        }
        if (i < s1) {
            int c = ccol[i];
            float4 k4 = kv4[(size_t)c * 64 + l];
            float4 v4 = kv4[(size_t)c * 64 + 32 + l];
            float p = q4.x * k4.x;
            p = fmaf(q4.y, k4.y, p);
            p = fmaf(q4.z, k4.z, p);
            p = fmaf(q4.w, k4.w, p);
            p += __shfl_xor(p, 1);
            p += __shfl_xor(p, 2);
            p += __shfl_xor(p, 4);
            p += __shfl_xor(p, 8);
            float e = expf(p);
            acc.x = fmaf(v4.x, e, acc.x);
            acc.y = fmaf(v4.y, e, acc.y);
            acc.z = fmaf(v4.z, e, acc.z);
            acc.w = fmaf(v4.w, e, acc.w);
            if ((l & 15) == 0) esum += (double)e;
        }
        ((float4*)U)[(size_t)n * 32 + l] = acc;
    }
    __shared__ double sd[2][8];
    if ((l & 15) == 0) sd[head][g] = esum;
    __syncthreads();
    if (threadIdx.x < 2) {
        double s = 0.0;
        for (int i2 = 0; i2 < 8; i2++) s += sd[threadIdx.x][i2];
        psum[(size_t)blockIdx.x * 2 + threadIdx.x] = s;
    }
}

// deterministic reduce of per-block partials -> sumf[2] (double)
__global__ void k_sum2(const double* __restrict__ psum, double* __restrict__ sumf, int P) {
    double s0 = 0.0, s1 = 0.0;
    for (int i = threadIdx.x; i < P; i += blockDim.x) {
        s0 += psum[2 * i];
        s1 += psum[2 * i + 1];
    }
    for (int off = 32; off; off >>= 1) {
        s0 += __shfl_xor(s0, off);
        s1 += __shfl_xor(s1, off);
    }
    __shared__ double sd[2][4];
    int w = threadIdx.x >> 6;
    if ((threadIdx.x & 63) == 0) { sd[0][w] = s0; sd[1][w] = s1; }
    __syncthreads();
    if (threadIdx.x == 0) {
        for (int i = 1; i < 4; i++) { s0 += sd[0][i]; s1 += sd[1][i]; }
        sumf[0] = s0;
        sumf[1] = s1;
    }
}

// ---------------- cr_initial (from x) + rows 0-3 of out + scale factor ----------------
__global__ void k_crout4(const float* __restrict__ x, const float* __restrict__ U,
                         const float* __restrict__ Wo, const float* __restrict__ bo,
                         const double* __restrict__ sumf, float* __restrict__ scalef) {
    __shared__ float xs[4 * 128];
    __shared__ float o4[4 * 64];
    __shared__ double crin_sh;
    int tid = threadIdx.x;  // 256
    xs[tid] = U[tid];
    xs[tid + 256] = U[tid + 256];
    if (tid < 64) {         // wave 0: cross-ratio of raw x rows 0..3
        int l = tid;
        const int pa[4] = {0, 1, 0, 1};
        const int pb[4] = {2, 3, 3, 2};
        double inner[4];
        for (int p = 0; p < 4; p++) {
            const float* a = x + pa[p] * 128;
            const float* b = x + pb[p] * 128;
            double s = (double)a[l] * (double)b[l];
            double t = (double)a[l + 64] * (double)b[l + 64];
            s += (l == 63) ? -t : t;
            for (int off = 32; off; off >>= 1) s += __shfl_xor(s, off);
            inner[p] = s;
        }
        if (l == 0) {
            double num = inner[0] * inner[1];
            double den = inner[2] * inner[3];
            if (fabs(den) < 1e-9) den = 1e-9;
            crin_sh = num / den;
        }
    }
    __syncthreads();
    int w = tid >> 6, o = tid & 63;
    float si0 = (float)(1.0 / sumf[0]);
    float si1 = (float)(1.0 / sumf[1]);
    const float* xr = xs + w * 128;
    const float* wr = Wo + (size_t)o * 128;
    float d0 = 0.f, d1 = 0.f;
    for (int j = 0; j < 64; j++) d0 = fmaf(xr[j], wr[j], d0);
    for (int j = 64; j < 128; j++) d1 = fmaf(xr[j], wr[j], d1);
    o4[w * 64 + o] = d0 * si0 + d1 * si1 + bo[o];
    __syncthreads();
    if (tid < 64) {
        int l = tid;
        const int pa[4] = {0, 1, 0, 1};
        const int pb[4] = {2, 3, 3, 2};
        double inner[4];
        for (int p = 0; p < 4; p++) {
            double t = (double)o4[pa[p] * 64 + l] * (double)o4[pb[p] * 64 + l];
            if (l == 63) t = -t;
            for (int off = 32; off; off >>= 1) t += __shfl_xor(t, off);
            inner[p] = t;
        }
        if (l == 0) {
            double num = inner[0] * inner[1];
            double den = inner[2] * inner[3];
            if (fabs(den) < 1e-9) den = 1e-9;
            double crc = num / den;
            if (fabs(crc) < 1e-9) crc = 1e-9;
            double ratio = crin_sh / crc;
            scalef[0] = (float)pow(fabs(ratio), 0.25);
        }
    }
}

// ---------------- final GEMM: out = ((U/sumf) @ Wo.T + bo) * scalef ----------------
__global__ void __launch_bounds__(256, 2)
k_out2(const float* __restrict__ U, const float* __restrict__ Wo,
       const float* __restrict__ bo, const double* __restrict__ sumf,
       const float* __restrict__ scalef, float* __restrict__ out, int N) {
    __shared__ float4 xs4[64 * 32];   // 32 KB
    __shared__ float4 ws4[64 * 16];   // 16 KB (one K-half of Wo)
    int tid = threadIdx.x;
    int rg = tid >> 4;       // 16 row-groups x 4 rows
    int cg = tid & 15;       // 16 col-groups x 4 cols
    int base = blockIdx.x * 64;

    float si0 = (float)(1.0 / sumf[0]);
    float si1 = (float)(1.0 / sumf[1]);
    const float4* U4 = (const float4*)U;
    const float4* Wo4 = (const float4*)Wo;

#pragma unroll
    for (int i2 = 0; i2 < 8; i2++) {
        int idx = tid + i2 * 256;
        int r = idx >> 5, kc = idx & 31;
        int row = base + r;
        float4 v = {0.f, 0.f, 0.f, 0.f};
        if (row < N) {
            v = U4[(size_t)row * 32 + kc];
            float si = (kc < 16) ? si0 : si1;
            v.x *= si; v.y *= si; v.z *= si; v.w *= si;
        }
        xs4[XS2(r, kc)] = v;
    }

    float acc[4][4];
#pragma unroll
    for (int i = 0; i < 4; i++)
#pragma unroll
        for (int j = 0; j < 4; j++) acc[i][j] = 0.f;

    for (int kp = 0; kp < 2; kp++) {
        __syncthreads();
#pragma unroll
        for (int i2 = 0; i2 < 4; i2++) {
            int idx = tid + i2 * 256;
            int c = idx >> 4, kc2 = idx & 15;
            ws4[WS2(c, kc2)] = Wo4[(size_t)c * 32 + kp * 16 + kc2];
        }
        __syncthreads();
        for (int kc2 = 0; kc2 < 16; kc2++) {
            int kc = kp * 16 + kc2;
            float4 xa[4], wb[4];
#pragma unroll
            for (int i = 0; i < 4; i++) xa[i] = xs4[XS2(rg * 4 + i, kc)];
#pragma unroll
            for (int j = 0; j < 4; j++) wb[j] = ws4[WS2(cg * 4 + j, kc2)];
#pragma unroll
            for (int i = 0; i < 4; i++)
#pragma unroll
                for (int j = 0; j < 4; j++) {
                    acc[i][j] = fmaf(xa[i].x, wb[j].x, acc[i][j]);
                    acc[i][j] = fmaf(xa[i].y, wb[j].y, acc[i][j]);
                    acc[i][j] = fmaf(xa[i].z, wb[j].z, acc[i][j]);
                    acc[i][j] = fmaf(xa[i].w, wb[j].w, acc[i][j]);
                }
        }
    }

    float4 bb = ((const float4*)bo)[cg];
    float sf = scalef[0];
#pragma unroll
    for (int i = 0; i < 4; i++) {
        int row = base + rg * 4 + i;
        if (row < N) {
            float4 o;
            o.x = (acc[i][0] + bb.x) * sf;
            o.y = (acc[i][1] + bb.y) * sf;
            o.z = (acc[i][2] + bb.z) * sf;
            o.w = (acc[i][3] + bb.w) * sf;
            ((float4*)(out + (size_t)row * 64))[cg] = o;
        }
    }
}

extern "C" void kernel_launch(void* const* d_in, const int* in_sizes, int n_in,
                              void* d_out, int out_size, void* d_ws, size_t ws_size,
                              hipStream_t stream) {
    const float* x  = (const float*)d_in[0];
    const int*   ei = (const int*)d_in[1];
    const float* Wq = (const float*)d_in[2];
    const float* bq = (const float*)d_in[3];
    const float* Wk = (const float*)d_in[4];
    const float* bk = (const float*)d_in[5];
    const float* Wv = (const float*)d_in[6];
    const float* bv = (const float*)d_in[7];
    const float* Wo = (const float*)d_in[8];
    const float* bo = (const float*)d_in[9];
    float* out = (float*)d_out;

    const int N = in_sizes[0] / 128;   // 100000
    const int E = in_sizes[1] / 2;
    const size_t NR = (size_t)N * 128;
    const int NB64 = (N + 63) / 64;    // 1563 tiled-GEMM blocks
    const int HB = 512;                // histogram-role blocks appended to k_qkv3
    const int GB = (N + 7) / 8;        // 12500 edge-kernel blocks
    const int T = (N + 1023) / 1024;

    float* qn = (float*)d_ws;          // N*128 ; reused as U after k_edge
    float* kv = qn + NR;               // N*256 (k|v interleaved per node)
    int* counts = (int*)(kv + NR * 2);         // N
    int* offs   = counts + N;                  // N+2
    int* cursor = offs + N + 2;                // N
    int* ccol   = cursor + N;                  // E
    double* psum = (double*)(ccol + E);        // GB*2 partial expsums
    int* tsum   = (int*)(psum + (size_t)GB * 2);  // T scan tiles
    double* sumf = (double*)(tsum + T + (T & 1)); // 2 doubles (8B aligned)
    float* scalef = (float*)(sumf + 2);           // 1

    float* U = qn;  // aggregation output aliases q (per-n read-then-write)

    hipMemsetAsync(counts, 0, (size_t)N * sizeof(int), stream);
    k_qkv3<<<NB64 + HB, 128, 0, stream>>>(x, Wq, bq, Wk, bk, Wv, bv,
                                          qn, kv, ei, counts, NB64, N, E);
    k_scan1<<<T, 256, 0, stream>>>(counts, offs, tsum, N);
    k_scan2<<<1, 64, 0, stream>>>(tsum, offs, T, N);
    k_scan3<<<(N + 255) / 256, 256, 0, stream>>>(offs, cursor, tsum, N);
    k_fill<<<1024, 256, 0, stream>>>(ei, cursor, ccol, E);
    k_edge<<<GB, 256, 0, stream>>>(qn, kv, offs, ccol, U, psum, N);
    k_sum2<<<1, 256, 0, stream>>>(psum, sumf, GB);
    k_crout4<<<1, 256, 0, stream>>>(x, U, Wo, bo, sumf, scalef);
    k_out2<<<NB64, 256, 0, stream>>>(U, Wo, bo, sumf, scalef, out, N);
}

// Round 2
// 565.342 us; speedup vs baseline: 1.0580x; 1.0580x over previous
//
#include <hip/hip_runtime.h>
#include <math.h>

#define EPSF 1e-9f
#define INV_SQRT128 0.08838834764831845f

// LDS swizzles for k_out2 (indices in float4 units)
#define XS2(r, kc) ((r) * 32 + ((kc) ^ (((r) >> 2) & 7)))   // kc < 32
#define WS2(c, kc) ((c) * 16 + ((kc) ^ (((c) >> 2) & 7)))   // kc < 16 (K-half)

typedef _Float16 half8 __attribute__((ext_vector_type(8)));
typedef float f32x4 __attribute__((ext_vector_type(4)));

// ---------------- W pre-pack: fp32 -> (hi fp16, lo fp16*4096) MFMA B-fragments ----------
// half8 slot t = ((kind*4+ks)*4+g)*128 + col  holds W[kind][col][ks*32+g*8 .. +8].
// Lane l of a wave reading col-tile ct then wants slot ((kind*4+ks)*4+(l>>4))*128+ct*16+(l&15)
// -> 4 x 256B contiguous segments per load instruction.
__global__ void k_wpack(const float* __restrict__ Wq, const float* __restrict__ Wk,
                        const float* __restrict__ Wv, half8* __restrict__ whi,
                        half8* __restrict__ wlo, float* __restrict__ w127) {
    int t = blockIdx.x * 256 + threadIdx.x;   // 6144 items
    if (t >= 6144) return;
    int col = t & 127, g = (t >> 7) & 3, ks = (t >> 9) & 3, kind = t >> 11;
    const float* W = (kind == 0) ? Wq : (kind == 1) ? Wk : Wv;
    const float4* W4 = (const float4*)W;
    float4 a = W4[col * 32 + ks * 8 + g * 2];
    float4 b = W4[col * 32 + ks * 8 + g * 2 + 1];
    float xv[8] = {a.x, a.y, a.z, a.w, b.x, b.y, b.z, b.w};
    half8 h, lo;
#pragma unroll
    for (int j = 0; j < 8; j++) {
        _Float16 hh = (_Float16)xv[j];
        h[j] = hh;
        lo[j] = (_Float16)((xv[j] - (float)hh) * 4096.0f);
    }
    whi[t] = h;
    wlo[t] = lo;
    if (ks == 3 && g == 3) w127[kind * 128 + col] = xv[7];   // W[col][127]
}

// ---------------- fused qkv via split-fp16 MFMA (+ histogram role) ----------------
// 256 thr = 4 independent waves, 16 rows each (64 rows/block). NO LDS, NO barriers.
// A (x rows) lives in registers as hi/lo fp16 frags; B streams from L2-resident packed W.
// 3-MFMA emulation: D = hiA*hiB + (hiA*loB + loA*hiB)/4096  (~22-bit mantissa).
// Row normalization folded into epilogue (round-1 verified):
//   c = rn*acc + x127*(1-rn)*W127[col] + bias.
// MFMA frag layout (16x16x32 f16): A lane l: row=l&15, k=(l>>4)*8+[0..7];
// B lane l: col=l&15, k=(l>>4)*8+[0..7]; D lane l: col=l&15, row=(l>>4)*4+reg.
__global__ void __launch_bounds__(256, 2)
k_qkvm(const float* __restrict__ x,
       const half8* __restrict__ whi, const half8* __restrict__ wlo,
       const float* __restrict__ w127,
       const float* __restrict__ bq, const float* __restrict__ bk,
       const float* __restrict__ bv,
       float* __restrict__ qn, float* __restrict__ kvout,
       const int* __restrict__ ei, int* __restrict__ counts,
       int NB, int N, int E) {
    if ((int)blockIdx.x >= NB) {   // histogram role
        int stride = ((int)gridDim.x - NB) * 256;
        for (int e = ((int)blockIdx.x - NB) * 256 + (int)threadIdx.x; e < E; e += stride)
            atomicAdd(&counts[ei[e]], 1);
        return;
    }
    int tid = threadIdx.x;
    int wv = tid >> 6;          // wave 0..3
    int l = tid & 63;
    int r = l & 15;             // A-row / out-col lane index
    int g = l >> 4;             // k-group / out-row group
    int rowbase = blockIdx.x * 64 + wv * 16;
    int row = min(rowbase + r, N - 1);

    // ---- load x fragments, build hi/lo, accumulate spatial norm partials ----
    const float4* x4 = (const float4*)x;
    half8 hiA[4], loA[4];
    float ssum = 0.f;
    float tl = 0.f;             // x[row][127], held by g==3 lanes
#pragma unroll
    for (int ks = 0; ks < 4; ks++) {
        float4 a = x4[(size_t)row * 32 + ks * 8 + g * 2];
        float4 b = x4[(size_t)row * 32 + ks * 8 + g * 2 + 1];
        float xv[8] = {a.x, a.y, a.z, a.w, b.x, b.y, b.z, b.w};
#pragma unroll
        for (int j = 0; j < 8; j++) {
            _Float16 hh = (_Float16)xv[j];
            hiA[ks][j] = hh;
            loA[ks][j] = (_Float16)((xv[j] - (float)hh) * 4096.0f);
            ssum += xv[j] * xv[j];
        }
        if (ks == 3 && g == 3) { tl = xv[7]; ssum -= xv[7] * xv[7]; }
    }
    // lanes {r, r+16, r+32, r+48} jointly hold row r's 128 elems
    ssum += __shfl_xor(ssum, 16);
    ssum += __shfl_xor(ssum, 32);
    float rn = 1.f / fmaxf(sqrtf(ssum), EPSF);
    float tla = __shfl(tl, 48 + r);          // broadcast x127 of row r
    float tc = tla * (1.f - rn);
    // per-output-row (g*4+j) constants: lane idx g*4+j (0..15) holds that row's rn/tc
    float rnj[4], tcj[4];
#pragma unroll
    for (int j = 0; j < 4; j++) {
        rnj[j] = __shfl(rn, g * 4 + j);
        tcj[j] = __shfl(tc, g * 4 + j);
    }

    const float* const bks[3] = {bq, bk, bv};
    bool lane15 = (r == 15);
    const f32x4 zz = {0.f, 0.f, 0.f, 0.f};

#pragma unroll
    for (int kind = 0; kind < 3; kind++) {
        f32x4 aM[8], aX[8];
#pragma unroll
        for (int ct = 0; ct < 8; ct++) { aM[ct] = zz; aX[ct] = zz; }
#pragma unroll
        for (int ct = 0; ct < 8; ct++) {
#pragma unroll
            for (int ks = 0; ks < 4; ks++) {
                int bi = ((kind * 4 + ks) * 4 + g) * 128 + ct * 16 + r;
                half8 hB = whi[bi];
                half8 lB = wlo[bi];
                aM[ct] = __builtin_amdgcn_mfma_f32_16x16x32_f16(hiA[ks], hB, aM[ct], 0, 0, 0);
                aX[ct] = __builtin_amdgcn_mfma_f32_16x16x32_f16(hiA[ks], lB, aX[ct], 0, 0, 0);
                aX[ct] = __builtin_amdgcn_mfma_f32_16x16x32_f16(loA[ks], hB, aX[ct], 0, 0, 0);
            }
        }
        // combine + normalization-correction + bias
        float cv[8][4];
#pragma unroll
        for (int ct = 0; ct < 8; ct++) {
            float wc = w127[kind * 128 + ct * 16 + r];
            float bb = bks[kind][ct * 16 + r];
#pragma unroll
            for (int j = 0; j < 4; j++) {
                float acc = aM[ct][j] + aX[ct][j] * (1.0f / 4096.0f);
                cv[ct][j] = fmaf(rnj[j], acc, fmaf(tcj[j], wc, bb));
            }
        }
        // per-(row,head) normalize for q/k; fold uhg minus + 1/sqrt(128) into q
        if (kind < 2) {
#pragma unroll
            for (int j = 0; j < 4; j++) {
                float s0 = 0.f, s1 = 0.f;
#pragma unroll
                for (int ct = 0; ct < 4; ct++) {
                    float c = cv[ct][j];
                    s0 += (ct == 3 && lane15) ? 0.f : c * c;
                }
#pragma unroll
                for (int ct = 4; ct < 8; ct++) {
                    float c = cv[ct][j];
                    s1 += (ct == 7 && lane15) ? 0.f : c * c;
                }
                s0 += __shfl_xor(s0, 1); s0 += __shfl_xor(s0, 2);
                s0 += __shfl_xor(s0, 4); s0 += __shfl_xor(s0, 8);
                s1 += __shfl_xor(s1, 1); s1 += __shfl_xor(s1, 2);
                s1 += __shfl_xor(s1, 4); s1 += __shfl_xor(s1, 8);
                float rh0 = 1.f / fmaxf(sqrtf(s0), EPSF);
                float rh1 = 1.f / fmaxf(sqrtf(s1), EPSF);
#pragma unroll
                for (int ct = 0; ct < 8; ct++) {
                    bool ist = ((ct & 3) == 3) && lane15;   // this head's time col
                    float rh = (ct < 4) ? rh0 : rh1;
                    if (!ist) cv[ct][j] *= rh;
                    if (kind == 0) {
                        if (ist) cv[ct][j] = -cv[ct][j];
                        cv[ct][j] *= INV_SQRT128;
                    }
                }
            }
        }
        // stores: lane writes col ct*16+r of rows rowbase+g*4+j
#pragma unroll
        for (int j = 0; j < 4; j++) {
            int orow = rowbase + g * 4 + j;
            if (orow < N) {
                float* dst = (kind == 0)
                    ? (qn + (size_t)orow * 128)
                    : (kvout + (size_t)orow * 256 + (kind == 2 ? 128 : 0));
#pragma unroll
                for (int ct = 0; ct < 8; ct++) dst[ct * 16 + r] = cv[ct][j];
            }
        }
    }
}

// ---------------- CSR build (scan + fill) ----------------
__global__ void k_scan1(const int* __restrict__ counts, int* __restrict__ offs,
                        int* __restrict__ tsum, int N) {
    __shared__ int sd[256];
    int tile = blockIdx.x;
    int t = threadIdx.x;
    int i0 = tile * 1024 + t * 4;
    int v[4];
    int lsum = 0;
    for (int j = 0; j < 4; j++) {
        int idx = i0 + j;
        v[j] = (idx < N) ? counts[idx] : 0;
        lsum += v[j];
    }
    sd[t] = lsum;
    __syncthreads();
    for (int off = 1; off < 256; off <<= 1) {
        int val = sd[t];
        int add = (t >= off) ? sd[t - off] : 0;
        __syncthreads();
        sd[t] = val + add;
        __syncthreads();
    }
    int excl = (t == 0) ? 0 : sd[t - 1];
    if (t == 255) tsum[tile] = sd[255];
    int run = excl;
    for (int j = 0; j < 4; j++) {
        int idx = i0 + j;
        if (idx < N) offs[idx] = run;
        run += v[j];
    }
}

__global__ void k_scan2(int* __restrict__ tsum, int* __restrict__ offs, int T, int N) {
    if (threadIdx.x == 0) {
        int run = 0;
        for (int i = 0; i < T; i++) {
            int t = tsum[i];
            tsum[i] = run;
            run += t;
        }
        offs[N] = run;
    }
}

__global__ void k_scan3(int* __restrict__ offs, int* __restrict__ cursor,
                        const int* __restrict__ tsum, int N) {
    int i = blockIdx.x * blockDim.x + threadIdx.x;
    if (i < N) {
        int o = offs[i] + tsum[i >> 10];
        offs[i] = o;
        cursor[i] = o;
    }
}

// stores the COLUMN id in CSR order
__global__ void k_fill(const int* __restrict__ ei, int* __restrict__ cursor,
                       int* __restrict__ ccol, int E) {
    int stride = blockDim.x * gridDim.x;
    for (int e = blockIdx.x * blockDim.x + threadIdx.x; e < E; e += stride) {
        int r = ei[e];
        int p = atomicAdd(&cursor[r], 1);
        ccol[p] = ei[E + e];
    }
}

// ---------------- fused edge pass: scores + exp + aggregate (unnormalized) ----------------
// kv[n] = [k-row | v-row] (256B-local gather per edge). Unroll-2 for MLP.
__global__ void k_edge(const float* __restrict__ qn, const float* __restrict__ kv,
                       const int* __restrict__ offs, const int* __restrict__ ccol,
                       float* __restrict__ U, double* __restrict__ psum, int N) {
    int g = threadIdx.x >> 5;            // 8 groups of 32 lanes
    int l = threadIdx.x & 31;
    int head = l >> 4;
    int n = blockIdx.x * 8 + g;
    double esum = 0.0;
    if (n < N) {
        float4 q4 = ((const float4*)qn)[(size_t)n * 32 + l];
        int s0 = offs[n], s1 = offs[n + 1];
        float4 acc = {0.f, 0.f, 0.f, 0.f};
        const float4* kv4 = (const float4*)kv;
        int i = s0;
        for (; i + 2 <= s1; i += 2) {
            int c0 = ccol[i];
            int c1 = ccol[i + 1];
            float4 ka = kv4[(size_t)c0 * 64 + l];
            float4 kb = kv4[(size_t)c1 * 64 + l];
            float4 va = kv4[(size_t)c0 * 64 + 32 + l];
            float4 vb = kv4[(size_t)c1 * 64 + 32 + l];
            float p0 = q4.x * ka.x;
            p0 = fmaf(q4.y, ka.y, p0);
            p0 = fmaf(q4.z, ka.z, p0);
            p0 = fmaf(q4.w, ka.w, p0);
            float p1 = q4.x * kb.x;
            p1 = fmaf(q4.y, kb.y, p1);
            p1 = fmaf(q4.z, kb.z, p1);
            p1 = fmaf(q4.w, kb.w, p1);
            p0 += __shfl_xor(p0, 1);
            p1 += __shfl_xor(p1, 1);
            p0 += __shfl_xor(p0, 2);
            p1 += __shfl_xor(p1, 2);
            p0 += __shfl_xor(p0, 4);
            p1 += __shfl_xor(p1, 4);
            p0 += __shfl_xor(p0, 8);
            p1 += __shfl_xor(p1, 8);
            float e0 = expf(p0);
            float e1 = expf(p1);
            acc.x = fmaf(va.x, e0, acc.x);
            acc.y = fmaf(va.y, e0, acc.y);
            acc.z = fmaf(va.z, e0, acc.z);
            acc.w = fmaf(va.w, e0, acc.w);
            acc.x = fmaf(vb.x, e1, acc.x);
            acc.y = fmaf(vb.y, e1, acc.y);
            acc.z = fmaf(vb.z, e1, acc.z);
            acc.w = fmaf(vb.w, e1, acc.w);
            if ((l & 15) == 0) esum += (double)e0 + (double)e1;
        }
        if (i < s1) {
            int c = ccol[i];
            float4 k4 = kv4[(size_t)c * 64 + l];
            float4 v4 = kv4[(size_t)c * 64 + 32 + l];
            float p = q4.x * k4.x;
            p = fmaf(q4.y, k4.y, p);
            p = fmaf(q4.z, k4.z, p);
            p = fmaf(q4.w, k4.w, p);
            p += __shfl_xor(p, 1);
            p += __shfl_xor(p, 2);
            p += __shfl_xor(p, 4);
            p += __shfl_xor(p, 8);
            float e = expf(p);
            acc.x = fmaf(v4.x, e, acc.x);
            acc.y = fmaf(v4.y, e, acc.y);
            acc.z = fmaf(v4.z, e, acc.z);
            acc.w = fmaf(v4.w, e, acc.w);
            if ((l & 15) == 0) esum += (double)e;
        }
        ((float4*)U)[(size_t)n * 32 + l] = acc;
    }
    __shared__ double sd[2][8];
    if ((l & 15) == 0) sd[head][g] = esum;
    __syncthreads();
    if (threadIdx.x < 2) {
        double s = 0.0;
        for (int i2 = 0; i2 < 8; i2++) s += sd[threadIdx.x][i2];
        psum[(size_t)blockIdx.x * 2 + threadIdx.x] = s;
    }
}

// deterministic reduce of per-block partials -> sumf[2] (double)
__global__ void k_sum2(const double* __restrict__ psum, double* __restrict__ sumf, int P) {
    double s0 = 0.0, s1 = 0.0;
    for (int i = threadIdx.x; i < P; i += blockDim.x) {
        s0 += psum[2 * i];
        s1 += psum[2 * i + 1];
    }
    for (int off = 32; off; off >>= 1) {
        s0 += __shfl_xor(s0, off);
        s1 += __shfl_xor(s1, off);
    }
    __shared__ double sd[2][4];
    int w = threadIdx.x >> 6;
    if ((threadIdx.x & 63) == 0) { sd[0][w] = s0; sd[1][w] = s1; }
    __syncthreads();
    if (threadIdx.x == 0) {
        for (int i = 1; i < 4; i++) { s0 += sd[0][i]; s1 += sd[1][i]; }
        sumf[0] = s0;
        sumf[1] = s1;
    }
}

// ---------------- cr_initial (from x) + rows 0-3 of out + scale factor ----------------
__global__ void k_crout4(const float* __restrict__ x, const float* __restrict__ U,
                         const float* __restrict__ Wo, const float* __restrict__ bo,
                         const double* __restrict__ sumf, float* __restrict__ scalef) {
    __shared__ float xs[4 * 128];
    __shared__ float o4[4 * 64];
    __shared__ double crin_sh;
    int tid = threadIdx.x;  // 256
    xs[tid] = U[tid];
    xs[tid + 256] = U[tid + 256];
    if (tid < 64) {         // wave 0: cross-ratio of raw x rows 0..3
        int l = tid;
        const int pa[4] = {0, 1, 0, 1};
        const int pb[4] = {2, 3, 3, 2};
        double inner[4];
        for (int p = 0; p < 4; p++) {
            const float* a = x + pa[p] * 128;
            const float* b = x + pb[p] * 128;
            double s = (double)a[l] * (double)b[l];
            double t = (double)a[l + 64] * (double)b[l + 64];
            s += (l == 63) ? -t : t;
            for (int off = 32; off; off >>= 1) s += __shfl_xor(s, off);
            inner[p] = s;
        }
        if (l == 0) {
            double num = inner[0] * inner[1];
            double den = inner[2] * inner[3];
            if (fabs(den) < 1e-9) den = 1e-9;
            crin_sh = num / den;
        }
    }
    __syncthreads();
    int w = tid >> 6, o = tid & 63;
    float si0 = (float)(1.0 / sumf[0]);
    float si1 = (float)(1.0 / sumf[1]);
    const float* xr = xs + w * 128;
    const float* wr = Wo + (size_t)o * 128;
    float d0 = 0.f, d1 = 0.f;
    for (int j = 0; j < 64; j++) d0 = fmaf(xr[j], wr[j], d0);
    for (int j = 64; j < 128; j++) d1 = fmaf(xr[j], wr[j], d1);
    o4[w * 64 + o] = d0 * si0 + d1 * si1 + bo[o];
    __syncthreads();
    if (tid < 64) {
        int l = tid;
        const int pa[4] = {0, 1, 0, 1};
        const int pb[4] = {2, 3, 3, 2};
        double inner[4];
        for (int p = 0; p < 4; p++) {
            double t = (double)o4[pa[p] * 64 + l] * (double)o4[pb[p] * 64 + l];
            if (l == 63) t = -t;
            for (int off = 32; off; off >>= 1) t += __shfl_xor(t, off);
            inner[p] = t;
        }
        if (l == 0) {
            double num = inner[0] * inner[1];
            double den = inner[2] * inner[3];
            if (fabs(den) < 1e-9) den = 1e-9;
            double crc = num / den;
            if (fabs(crc) < 1e-9) crc = 1e-9;
            double ratio = crin_sh / crc;
            scalef[0] = (float)pow(fabs(ratio), 0.25);
        }
    }
}

// ---------------- final GEMM: out = ((U/sumf) @ Wo.T + bo) * scalef ----------------
__global__ void __launch_bounds__(256, 2)
k_out2(const float* __restrict__ U, const float* __restrict__ Wo,
       const float* __restrict__ bo, const double* __restrict__ sumf,
       const float* __restrict__ scalef, float* __restrict__ out, int N) {
    __shared__ float4 xs4[64 * 32];   // 32 KB
    __shared__ float4 ws4[64 * 16];   // 16 KB (one K-half of Wo)
    int tid = threadIdx.x;
    int rg = tid >> 4;       // 16 row-groups x 4 rows
    int cg = tid & 15;       // 16 col-groups x 4 cols
    int base = blockIdx.x * 64;

    float si0 = (float)(1.0 / sumf[0]);
    float si1 = (float)(1.0 / sumf[1]);
    const float4* U4 = (const float4*)U;
    const float4* Wo4 = (const float4*)Wo;

#pragma unroll
    for (int i2 = 0; i2 < 8; i2++) {
        int idx = tid + i2 * 256;
        int r = idx >> 5, kc = idx & 31;
        int row = base + r;
        float4 v = {0.f, 0.f, 0.f, 0.f};
        if (row < N) {
            v = U4[(size_t)row * 32 + kc];
            float si = (kc < 16) ? si0 : si1;
            v.x *= si; v.y *= si; v.z *= si; v.w *= si;
        }
        xs4[XS2(r, kc)] = v;
    }

    float acc[4][4];
#pragma unroll
    for (int i = 0; i < 4; i++)
#pragma unroll
        for (int j = 0; j < 4; j++) acc[i][j] = 0.f;

    for (int kp = 0; kp < 2; kp++) {
        __syncthreads();
#pragma unroll
        for (int i2 = 0; i2 < 4; i2++) {
            int idx = tid + i2 * 256;
            int c = idx >> 4, kc2 = idx & 15;
            ws4[WS2(c, kc2)] = Wo4[(size_t)c * 32 + kp * 16 + kc2];
        }
        __syncthreads();
        for (int kc2 = 0; kc2 < 16; kc2++) {
            int kc = kp * 16 + kc2;
            float4 xa[4], wb[4];
#pragma unroll
            for (int i = 0; i < 4; i++) xa[i] = xs4[XS2(rg * 4 + i, kc)];
#pragma unroll
            for (int j = 0; j < 4; j++) wb[j] = ws4[WS2(cg * 4 + j, kc2)];
#pragma unroll
            for (int i = 0; i < 4; i++)
#pragma unroll
                for (int j = 0; j < 4; j++) {
                    acc[i][j] = fmaf(xa[i].x, wb[j].x, acc[i][j]);
                    acc[i][j] = fmaf(xa[i].y, wb[j].y, acc[i][j]);
                    acc[i][j] = fmaf(xa[i].z, wb[j].z, acc[i][j]);
                    acc[i][j] = fmaf(xa[i].w, wb[j].w, acc[i][j]);
                }
        }
    }

    float4 bb = ((const float4*)bo)[cg];
    float sf = scalef[0];
#pragma unroll
    for (int i = 0; i < 4; i++) {
        int row = base + rg * 4 + i;
        if (row < N) {
            float4 o;
            o.x = (acc[i][0] + bb.x) * sf;
            o.y = (acc[i][1] + bb.y) * sf;
            o.z = (acc[i][2] + bb.z) * sf;
            o.w = (acc[i][3] + bb.w) * sf;
            ((float4*)(out + (size_t)row * 64))[cg] = o;
        }
    }
}

extern "C" void kernel_launch(void* const* d_in, const int* in_sizes, int n_in,
                              void* d_out, int out_size, void* d_ws, size_t ws_size,
                              hipStream_t stream) {
    const float* x  = (const float*)d_in[0];
    const int*   ei = (const int*)d_in[1];
    const float* Wq = (const float*)d_in[2];
    const float* bq = (const float*)d_in[3];
    const float* Wk = (const float*)d_in[4];
    const float* bk = (const float*)d_in[5];
    const float* Wv = (const float*)d_in[6];
    const float* bv = (const float*)d_in[7];
    const float* Wo = (const float*)d_in[8];
    const float* bo = (const float*)d_in[9];
    float* out = (float*)d_out;

    const int N = in_sizes[0] / 128;   // 100000
    const int E = in_sizes[1] / 2;
    const size_t NR = (size_t)N * 128;
    const int NB64 = (N + 63) / 64;    // 1563 MFMA-GEMM blocks
    const int HB = 512;                // histogram-role blocks appended to k_qkvm
    const int GB = (N + 7) / 8;        // 12500 edge-kernel blocks
    const int T = (N + 1023) / 1024;

    float* qn = (float*)d_ws;          // N*128 ; reused as U after k_edge
    float* kv = qn + NR;               // N*256 (k|v interleaved per node)
    int* counts = (int*)(kv + NR * 2);         // N
    int* offs   = counts + N;                  // N+2
    int* cursor = offs + N + 2;                // N
    int* ccol   = cursor + N;                  // E
    double* psum = (double*)(ccol + E);        // GB*2 partial expsums
    int* tsum   = (int*)(psum + (size_t)GB * 2);  // T scan tiles
    double* sumf = (double*)(tsum + T + (T & 1)); // 2 doubles (8B aligned)
    float* scalef = (float*)(sumf + 2);           // 1

    // packed W hi/lo fragments live in ccol's space (ccol is only written by
    // k_fill, which runs AFTER k_qkvm has consumed whi/wlo). ~198 KB << 4 MB.
    uintptr_t pw = ((uintptr_t)ccol + 15) & ~(uintptr_t)15;
    half8* whi = (half8*)pw;                   // 6144 * 16B
    half8* wlo = whi + 6144;                   // 6144 * 16B
    float* w127 = (float*)(wlo + 6144);        // 3*128 floats

    float* U = qn;  // aggregation output aliases q (per-n read-then-write)

    hipMemsetAsync(counts, 0, (size_t)N * sizeof(int), stream);
    k_wpack<<<24, 256, 0, stream>>>(Wq, Wk, Wv, whi, wlo, w127);
    k_qkvm<<<NB64 + HB, 256, 0, stream>>>(x, whi, wlo, w127, bq, bk, bv,
                                          qn, kv, ei, counts, NB64, N, E);
    k_scan1<<<T, 256, 0, stream>>>(counts, offs, tsum, N);
    k_scan2<<<1, 64, 0, stream>>>(tsum, offs, T, N);
    k_scan3<<<(N + 255) / 256, 256, 0, stream>>>(offs, cursor, tsum, N);
    k_fill<<<1024, 256, 0, stream>>>(ei, cursor, ccol, E);
    k_edge<<<GB, 256, 0, stream>>>(qn, kv, offs, ccol, U, psum, N);
    k_sum2<<<1, 256, 0, stream>>>(psum, sumf, GB);
    k_crout4<<<1, 256, 0, stream>>>(x, U, Wo, bo, sumf, scalef);
    k_out2<<<NB64, 256, 0, stream>>>(U, Wo, bo, sumf, scalef, out, N);
}

// Round 3
// 496.531 us; speedup vs baseline: 1.2046x; 1.1386x over previous
//
#include <hip/hip_runtime.h>
#include <math.h>

#define EPSF 1e-9f
#define INV_SQRT128 0.08838834764831845f

// LDS swizzles for k_out2 (indices in float4 units)
#define XS2(r, kc) ((r) * 32 + ((kc) ^ (((r) >> 2) & 7)))   // kc < 32
#define WS2(c, kc) ((c) * 16 + ((kc) ^ (((c) >> 2) & 7)))   // kc < 16 (K-half)

typedef _Float16 half8 __attribute__((ext_vector_type(8)));
typedef float f32x4 __attribute__((ext_vector_type(4)));

// async global->LDS, 16B per lane: lane l reads g[l], HW writes lds_base + l*16
__device__ __forceinline__ void gl_lds16(const void* g, void* l) {
    __builtin_amdgcn_global_load_lds((const __attribute__((address_space(1))) void*)g,
                                     (__attribute__((address_space(3))) void*)l, 16, 0, 0);
}

// ---------------- W pre-pack: fp32 -> (hi fp16, lo fp16*4096) MFMA B-fragments ----------
// half8 slot t = ((kind*4+ks)*4+g)*128 + col  holds W[kind][col][ks*32+g*8 .. +8].
__global__ void k_wpack(const float* __restrict__ Wq, const float* __restrict__ Wk,
                        const float* __restrict__ Wv, half8* __restrict__ whi,
                        half8* __restrict__ wlo, float* __restrict__ w127) {
    int t = blockIdx.x * 256 + threadIdx.x;   // 6144 items
    if (t >= 6144) return;
    int col = t & 127, g = (t >> 7) & 3, ks = (t >> 9) & 3, kind = t >> 11;
    const float* W = (kind == 0) ? Wq : (kind == 1) ? Wk : Wv;
    const float4* W4 = (const float4*)W;
    float4 a = W4[col * 32 + ks * 8 + g * 2];
    float4 b = W4[col * 32 + ks * 8 + g * 2 + 1];
    float xv[8] = {a.x, a.y, a.z, a.w, b.x, b.y, b.z, b.w};
    half8 h, lo;
#pragma unroll
    for (int j = 0; j < 8; j++) {
        _Float16 hh = (_Float16)xv[j];
        h[j] = hh;
        lo[j] = (_Float16)((xv[j] - (float)hh) * 4096.0f);
    }
    whi[t] = h;
    wlo[t] = lo;
    if (ks == 3 && g == 3) w127[kind * 128 + col] = xv[7];   // W[col][127]
}

// ---------------- fused qkv via split-fp16 MFMA, B staged in LDS ----------------
// 256 thr = 4 waves x 32 rows = 128 rows/block. Histogram blocks interleaved 1-in-3
// (b%3==2) so the 1M edge atomics overlap the GEMM instead of trailing it.
// B (packed W hi/lo, 64KB/kind) is bulk-copied global->LDS once per block, then read
// as ds_read_b128 fragments: no L2 latency in the MFMA loop (round-2 was
// latency-bound on per-wave L2 B-loads: all pipes <20%).
// 3-MFMA split-fp16: D = hiA*hiB + (hiA*loB + loA*hiB)/4096 (~22-bit mantissa).
// Normalization folded into epilogue: c = rn*acc + x127*(1-rn)*W127[col] + bias.
__global__ void __launch_bounds__(256, 2)
k_qkvm(const float* __restrict__ x,
       const half8* __restrict__ whi, const half8* __restrict__ wlo,
       const float* __restrict__ w127,
       const float* __restrict__ bq, const float* __restrict__ bk,
       const float* __restrict__ bv,
       float* __restrict__ qn, float* __restrict__ kvout,
       const int* __restrict__ ei, int* __restrict__ counts,
       int N, int E) {
    int b = (int)blockIdx.x;
    if (b % 3 == 2) {                 // histogram role, interleaved
        int HB = (int)gridDim.x / 3;
        int stride = HB * 256;
        for (int e = (b / 3) * 256 + (int)threadIdx.x; e < E; e += stride)
            atomicAdd(&counts[ei[e]], 1);
        return;
    }
    int gb = b - (b + 1) / 3;         // GEMM block id

    __shared__ half8 bsh[4096];       // 64 KB: [0..2048) hi, [2048..4096) lo

    int tid = threadIdx.x;
    int wv = tid >> 6;                // wave 0..3
    int l = tid & 63;
    int r = l & 15;                   // A-row / out-col lane index
    int g = l >> 4;                   // k-group / out-row group
    int rowbase = gb * 128 + wv * 32;
    const float4* x4 = (const float4*)x;

    // ---- issue kind-0 B staging first (latency overlaps x processing) ----
    {
        const half8* sH = whi + wv * 512;
        const half8* sL = wlo + wv * 512;
#pragma unroll
        for (int i = 0; i < 8; i++) {
            gl_lds16(sH + i * 64 + l, bsh + wv * 512 + i * 64);
            gl_lds16(sL + i * 64 + l, bsh + 2048 + wv * 512 + i * 64);
        }
    }

    // ---- load x for 2 row-tiles, build hi/lo frags, fold normalization ----
    half8 hiA[2][4], loA[2][4];
    float rnj[2][4], tcj[2][4];
#pragma unroll
    for (int t = 0; t < 2; t++) {
        int row = min(rowbase + t * 16 + r, N - 1);
        float ssum = 0.f, tl = 0.f;
#pragma unroll
        for (int ks = 0; ks < 4; ks++) {
            float4 a = x4[(size_t)row * 32 + ks * 8 + g * 2];
            float4 bb = x4[(size_t)row * 32 + ks * 8 + g * 2 + 1];
            float xv[8] = {a.x, a.y, a.z, a.w, bb.x, bb.y, bb.z, bb.w};
#pragma unroll
            for (int j = 0; j < 8; j++) {
                _Float16 hh = (_Float16)xv[j];
                hiA[t][ks][j] = hh;
                loA[t][ks][j] = (_Float16)((xv[j] - (float)hh) * 4096.0f);
                ssum += xv[j] * xv[j];
            }
            if (ks == 3 && g == 3) { tl = xv[7]; ssum -= xv[7] * xv[7]; }
        }
        ssum += __shfl_xor(ssum, 16);
        ssum += __shfl_xor(ssum, 32);
        float rn = 1.f / fmaxf(sqrtf(ssum), EPSF);
        float tla = __shfl(tl, 48 + r);        // x127 of row (t, r)
        float tc = tla * (1.f - rn);
#pragma unroll
        for (int j = 0; j < 4; j++) {
            rnj[t][j] = __shfl(rn, g * 4 + j);
            tcj[t][j] = __shfl(tc, g * 4 + j);
        }
    }

    asm volatile("s_waitcnt vmcnt(0)" ::: "memory");
    __syncthreads();                  // kind-0 B resident in LDS

    const float* const bks[3] = {bq, bk, bv};
    bool lane15 = (r == 15);
    const f32x4 zz = {0.f, 0.f, 0.f, 0.f};
    int dsbase = g * 128 + r;         // half8-slot base for this lane

    for (int kind = 0; kind < 3; kind++) {
        // per-kind epilogue constants (issued early, overlap MFMA phase)
        float wcA[2][4], bbA[2][4];
#pragma unroll
        for (int h = 0; h < 2; h++)
#pragma unroll
            for (int ct = 0; ct < 4; ct++) {
                int col = (h * 4 + ct) * 16 + r;
                wcA[h][ct] = w127[kind * 128 + col];
                bbA[h][ct] = bks[kind][col];
            }

#pragma unroll
        for (int h = 0; h < 2; h++) {
            f32x4 aM[2][4], aX[2][4];
#pragma unroll
            for (int t = 0; t < 2; t++)
#pragma unroll
                for (int ct = 0; ct < 4; ct++) { aM[t][ct] = zz; aX[t][ct] = zz; }

#pragma unroll
            for (int ks = 0; ks < 4; ks++) {
                half8 hB[4], lB[4];
#pragma unroll
                for (int ct = 0; ct < 4; ct++) {
                    int bi = dsbase + ks * 512 + (h * 4 + ct) * 16;
                    hB[ct] = bsh[bi];
                    lB[ct] = bsh[2048 + bi];
                }
#pragma unroll
                for (int ct = 0; ct < 4; ct++) {
                    aM[0][ct] = __builtin_amdgcn_mfma_f32_16x16x32_f16(hiA[0][ks], hB[ct], aM[0][ct], 0, 0, 0);
                    aM[1][ct] = __builtin_amdgcn_mfma_f32_16x16x32_f16(hiA[1][ks], hB[ct], aM[1][ct], 0, 0, 0);
                    aX[0][ct] = __builtin_amdgcn_mfma_f32_16x16x32_f16(hiA[0][ks], lB[ct], aX[0][ct], 0, 0, 0);
                    aX[0][ct] = __builtin_amdgcn_mfma_f32_16x16x32_f16(loA[0][ks], hB[ct], aX[0][ct], 0, 0, 0);
                    aX[1][ct] = __builtin_amdgcn_mfma_f32_16x16x32_f16(hiA[1][ks], lB[ct], aX[1][ct], 0, 0, 0);
                    aX[1][ct] = __builtin_amdgcn_mfma_f32_16x16x32_f16(loA[1][ks], hB[ct], aX[1][ct], 0, 0, 0);
                }
            }

            // epilogue for head h: combine, norm-correct, q/k head-normalize, store
#pragma unroll
            for (int t = 0; t < 2; t++) {
                float cv[4][4];       // [ct][j]
#pragma unroll
                for (int ct = 0; ct < 4; ct++)
#pragma unroll
                    for (int j = 0; j < 4; j++) {
                        float acc = aM[t][ct][j] + aX[t][ct][j] * (1.0f / 4096.0f);
                        cv[ct][j] = fmaf(rnj[t][j], acc, fmaf(tcj[t][j], wcA[h][ct], bbA[h][ct]));
                    }
                if (kind < 2) {
#pragma unroll
                    for (int j = 0; j < 4; j++) {
                        float ss = 0.f;
#pragma unroll
                        for (int ct = 0; ct < 4; ct++) {
                            float c = cv[ct][j];
                            ss += (ct == 3 && lane15) ? 0.f : c * c;
                        }
                        ss += __shfl_xor(ss, 1);
                        ss += __shfl_xor(ss, 2);
                        ss += __shfl_xor(ss, 4);
                        ss += __shfl_xor(ss, 8);
                        float rh = 1.f / fmaxf(sqrtf(ss), EPSF);
#pragma unroll
                        for (int ct = 0; ct < 4; ct++) {
                            bool ist = (ct == 3) && lane15;
                            if (!ist) cv[ct][j] *= rh;
                            if (kind == 0) {
                                if (ist) cv[ct][j] = -cv[ct][j];
                                cv[ct][j] *= INV_SQRT128;
                            }
                        }
                    }
                }
#pragma unroll
                for (int j = 0; j < 4; j++) {
                    int row = rowbase + t * 16 + g * 4 + j;
                    if (row < N) {
                        float* dst = (kind == 0)
                            ? (qn + (size_t)row * 128)
                            : (kvout + (size_t)row * 256 + (kind == 2 ? 128 : 0));
#pragma unroll
                        for (int ct = 0; ct < 4; ct++)
                            dst[(h * 4 + ct) * 16 + r] = cv[ct][j];
                    }
                }
            }
        }

        if (kind < 2) {               // restage B for next kind
            __syncthreads();          // all waves done reading bsh
            const half8* sH = whi + (kind + 1) * 2048 + wv * 512;
            const half8* sL = wlo + (kind + 1) * 2048 + wv * 512;
#pragma unroll
            for (int i = 0; i < 8; i++) {
                gl_lds16(sH + i * 64 + l, bsh + wv * 512 + i * 64);
                gl_lds16(sL + i * 64 + l, bsh + 2048 + wv * 512 + i * 64);
            }
            asm volatile("s_waitcnt vmcnt(0)" ::: "memory");
            __syncthreads();
        }
    }
}

// ---------------- CSR build (scan + fill) ----------------
__global__ void k_scan1(const int* __restrict__ counts, int* __restrict__ offs,
                        int* __restrict__ tsum, int N) {
    __shared__ int sd[256];
    int tile = blockIdx.x;
    int t = threadIdx.x;
    int i0 = tile * 1024 + t * 4;
    int v[4];
    int lsum = 0;
    for (int j = 0; j < 4; j++) {
        int idx = i0 + j;
        v[j] = (idx < N) ? counts[idx] : 0;
        lsum += v[j];
    }
    sd[t] = lsum;
    __syncthreads();
    for (int off = 1; off < 256; off <<= 1) {
        int val = sd[t];
        int add = (t >= off) ? sd[t - off] : 0;
        __syncthreads();
        sd[t] = val + add;
        __syncthreads();
    }
    int excl = (t == 0) ? 0 : sd[t - 1];
    if (t == 255) tsum[tile] = sd[255];
    int run = excl;
    for (int j = 0; j < 4; j++) {
        int idx = i0 + j;
        if (idx < N) offs[idx] = run;
        run += v[j];
    }
}

__global__ void k_scan2(int* __restrict__ tsum, int* __restrict__ offs, int T, int N) {
    if (threadIdx.x == 0) {
        int run = 0;
        for (int i = 0; i < T; i++) {
            int t = tsum[i];
            tsum[i] = run;
            run += t;
        }
        offs[N] = run;
    }
}

__global__ void k_scan3(int* __restrict__ offs, int* __restrict__ cursor,
                        const int* __restrict__ tsum, int N) {
    int i = blockIdx.x * blockDim.x + threadIdx.x;
    if (i < N) {
        int o = offs[i] + tsum[i >> 10];
        offs[i] = o;
        cursor[i] = o;
    }
}

// stores the COLUMN id in CSR order
__global__ void k_fill(const int* __restrict__ ei, int* __restrict__ cursor,
                       int* __restrict__ ccol, int E) {
    int stride = blockDim.x * gridDim.x;
    for (int e = blockIdx.x * blockDim.x + threadIdx.x; e < E; e += stride) {
        int r = ei[e];
        int p = atomicAdd(&cursor[r], 1);
        ccol[p] = ei[E + e];
    }
}

// ---------------- fused edge pass: scores + exp + aggregate (unnormalized) ----------------
__global__ void k_edge(const float* __restrict__ qn, const float* __restrict__ kv,
                       const int* __restrict__ offs, const int* __restrict__ ccol,
                       float* __restrict__ U, double* __restrict__ psum, int N) {
    int g = threadIdx.x >> 5;            // 8 groups of 32 lanes
    int l = threadIdx.x & 31;
    int head = l >> 4;
    int n = blockIdx.x * 8 + g;
    double esum = 0.0;
    if (n < N) {
        float4 q4 = ((const float4*)qn)[(size_t)n * 32 + l];
        int s0 = offs[n], s1 = offs[n + 1];
        float4 acc = {0.f, 0.f, 0.f, 0.f};
        const float4* kv4 = (const float4*)kv;
        int i = s0;
        for (; i + 2 <= s1; i += 2) {
            int c0 = ccol[i];
            int c1 = ccol[i + 1];
            float4 ka = kv4[(size_t)c0 * 64 + l];
            float4 kb = kv4[(size_t)c1 * 64 + l];
            float4 va = kv4[(size_t)c0 * 64 + 32 + l];
            float4 vb = kv4[(size_t)c1 * 64 + 32 + l];
            float p0 = q4.x * ka.x;
            p0 = fmaf(q4.y, ka.y, p0);
            p0 = fmaf(q4.z, ka.z, p0);
            p0 = fmaf(q4.w, ka.w, p0);
            float p1 = q4.x * kb.x;
            p1 = fmaf(q4.y, kb.y, p1);
            p1 = fmaf(q4.z, kb.z, p1);
            p1 = fmaf(q4.w, kb.w, p1);
            p0 += __shfl_xor(p0, 1);
            p1 += __shfl_xor(p1, 1);
            p0 += __shfl_xor(p0, 2);
            p1 += __shfl_xor(p1, 2);
            p0 += __shfl_xor(p0, 4);
            p1 += __shfl_xor(p1, 4);
            p0 += __shfl_xor(p0, 8);
            p1 += __shfl_xor(p1, 8);
            float e0 = expf(p0);
            float e1 = expf(p1);
            acc.x = fmaf(va.x, e0, acc.x);
            acc.y = fmaf(va.y, e0, acc.y);
            acc.z = fmaf(va.z, e0, acc.z);
            acc.w = fmaf(va.w, e0, acc.w);
            acc.x = fmaf(vb.x, e1, acc.x);
            acc.y = fmaf(vb.y, e1, acc.y);
            acc.z = fmaf(vb.z, e1, acc.z);
            acc.w = fmaf(vb.w, e1, acc.w);
            if ((l & 15) == 0) esum += (double)e0 + (double)e1;
        }
        if (i < s1) {
            int c = ccol[i];
            float4 k4 = kv4[(size_t)c * 64 + l];
            float4 v4 = kv4[(size_t)c * 64 + 32 + l];
            float p = q4.x * k4.x;
            p = fmaf(q4.y, k4.y, p);
            p = fmaf(q4.z, k4.z, p);
            p = fmaf(q4.w, k4.w, p);
            p += __shfl_xor(p, 1);
            p += __shfl_xor(p, 2);
            p += __shfl_xor(p, 4);
            p += __shfl_xor(p, 8);
            float e = expf(p);
            acc.x = fmaf(v4.x, e, acc.x);
            acc.y = fmaf(v4.y, e, acc.y);
            acc.z = fmaf(v4.z, e, acc.z);
            acc.w = fmaf(v4.w, e, acc.w);
            if ((l & 15) == 0) esum += (double)e;
        }
        ((float4*)U)[(size_t)n * 32 + l] = acc;
    }
    __shared__ double sd[2][8];
    if ((l & 15) == 0) sd[head][g] = esum;
    __syncthreads();
    if (threadIdx.x < 2) {
        double s = 0.0;
        for (int i2 = 0; i2 < 8; i2++) s += sd[threadIdx.x][i2];
        psum[(size_t)blockIdx.x * 2 + threadIdx.x] = s;
    }
}

// deterministic reduce of per-block partials -> sumf[2] (double)
__global__ void k_sum2(const double* __restrict__ psum, double* __restrict__ sumf, int P) {
    double s0 = 0.0, s1 = 0.0;
    for (int i = threadIdx.x; i < P; i += blockDim.x) {
        s0 += psum[2 * i];
        s1 += psum[2 * i + 1];
    }
    for (int off = 32; off; off >>= 1) {
        s0 += __shfl_xor(s0, off);
        s1 += __shfl_xor(s1, off);
    }
    __shared__ double sd[2][4];
    int w = threadIdx.x >> 6;
    if ((threadIdx.x & 63) == 0) { sd[0][w] = s0; sd[1][w] = s1; }
    __syncthreads();
    if (threadIdx.x == 0) {
        for (int i = 1; i < 4; i++) { s0 += sd[0][i]; s1 += sd[1][i]; }
        sumf[0] = s0;
        sumf[1] = s1;
    }
}

// ---------------- cr_initial (from x) + rows 0-3 of out + scale factor ----------------
__global__ void k_crout4(const float* __restrict__ x, const float* __restrict__ U,
                         const float* __restrict__ Wo, const float* __restrict__ bo,
                         const double* __restrict__ sumf, float* __restrict__ scalef) {
    __shared__ float xs[4 * 128];
    __shared__ float o4[4 * 64];
    __shared__ double crin_sh;
    int tid = threadIdx.x;  // 256
    xs[tid] = U[tid];
    xs[tid + 256] = U[tid + 256];
    if (tid < 64) {         // wave 0: cross-ratio of raw x rows 0..3
        int l = tid;
        const int pa[4] = {0, 1, 0, 1};
        const int pb[4] = {2, 3, 3, 2};
        double inner[4];
        for (int p = 0; p < 4; p++) {
            const float* a = x + pa[p] * 128;
            const float* b = x + pb[p] * 128;
            double s = (double)a[l] * (double)b[l];
            double t = (double)a[l + 64] * (double)b[l + 64];
            s += (l == 63) ? -t : t;
            for (int off = 32; off; off >>= 1) s += __shfl_xor(s, off);
            inner[p] = s;
        }
        if (l == 0) {
            double num = inner[0] * inner[1];
            double den = inner[2] * inner[3];
            if (fabs(den) < 1e-9) den = 1e-9;
            crin_sh = num / den;
        }
    }
    __syncthreads();
    int w = tid >> 6, o = tid & 63;
    float si0 = (float)(1.0 / sumf[0]);
    float si1 = (float)(1.0 / sumf[1]);
    const float* xr = xs + w * 128;
    const float* wr = Wo + (size_t)o * 128;
    float d0 = 0.f, d1 = 0.f;
    for (int j = 0; j < 64; j++) d0 = fmaf(xr[j], wr[j], d0);
    for (int j = 64; j < 128; j++) d1 = fmaf(xr[j], wr[j], d1);
    o4[w * 64 + o] = d0 * si0 + d1 * si1 + bo[o];
    __syncthreads();
    if (tid < 64) {
        int l = tid;
        const int pa[4] = {0, 1, 0, 1};
        const int pb[4] = {2, 3, 3, 2};
        double inner[4];
        for (int p = 0; p < 4; p++) {
            double t = (double)o4[pa[p] * 64 + l] * (double)o4[pb[p] * 64 + l];
            if (l == 63) t = -t;
            for (int off = 32; off; off >>= 1) t += __shfl_xor(t, off);
            inner[p] = t;
        }
        if (l == 0) {
            double num = inner[0] * inner[1];
            double den = inner[2] * inner[3];
            if (fabs(den) < 1e-9) den = 1e-9;
            double crc = num / den;
            if (fabs(crc) < 1e-9) crc = 1e-9;
            double ratio = crin_sh / crc;
            scalef[0] = (float)pow(fabs(ratio), 0.25);
        }
    }
}

// ---------------- final GEMM: out = ((U/sumf) @ Wo.T + bo) * scalef ----------------
__global__ void __launch_bounds__(256, 2)
k_out2(const float* __restrict__ U, const float* __restrict__ Wo,
       const float* __restrict__ bo, const double* __restrict__ sumf,
       const float* __restrict__ scalef, float* __restrict__ out, int N) {
    __shared__ float4 xs4[64 * 32];   // 32 KB
    __shared__ float4 ws4[64 * 16];   // 16 KB (one K-half of Wo)
    int tid = threadIdx.x;
    int rg = tid >> 4;       // 16 row-groups x 4 rows
    int cg = tid & 15;       // 16 col-groups x 4 cols
    int base = blockIdx.x * 64;

    float si0 = (float)(1.0 / sumf[0]);
    float si1 = (float)(1.0 / sumf[1]);
    const float4* U4 = (const float4*)U;
    const float4* Wo4 = (const float4*)Wo;

#pragma unroll
    for (int i2 = 0; i2 < 8; i2++) {
        int idx = tid + i2 * 256;
        int r = idx >> 5, kc = idx & 31;
        int row = base + r;
        float4 v = {0.f, 0.f, 0.f, 0.f};
        if (row < N) {
            v = U4[(size_t)row * 32 + kc];
            float si = (kc < 16) ? si0 : si1;
            v.x *= si; v.y *= si; v.z *= si; v.w *= si;
        }
        xs4[XS2(r, kc)] = v;
    }

    float acc[4][4];
#pragma unroll
    for (int i = 0; i < 4; i++)
#pragma unroll
        for (int j = 0; j < 4; j++) acc[i][j] = 0.f;

    for (int kp = 0; kp < 2; kp++) {
        __syncthreads();
#pragma unroll
        for (int i2 = 0; i2 < 4; i2++) {
            int idx = tid + i2 * 256;
            int c = idx >> 4, kc2 = idx & 15;
            ws4[WS2(c, kc2)] = Wo4[(size_t)c * 32 + kp * 16 + kc2];
        }
        __syncthreads();
        for (int kc2 = 0; kc2 < 16; kc2++) {
            int kc = kp * 16 + kc2;
            float4 xa[4], wb[4];
#pragma unroll
            for (int i = 0; i < 4; i++) xa[i] = xs4[XS2(rg * 4 + i, kc)];
#pragma unroll
            for (int j = 0; j < 4; j++) wb[j] = ws4[WS2(cg * 4 + j, kc2)];
#pragma unroll
            for (int i = 0; i < 4; i++)
#pragma unroll
                for (int j = 0; j < 4; j++) {
                    acc[i][j] = fmaf(xa[i].x, wb[j].x, acc[i][j]);
                    acc[i][j] = fmaf(xa[i].y, wb[j].y, acc[i][j]);
                    acc[i][j] = fmaf(xa[i].z, wb[j].z, acc[i][j]);
                    acc[i][j] = fmaf(xa[i].w, wb[j].w, acc[i][j]);
                }
        }
    }

    float4 bb = ((const float4*)bo)[cg];
    float sf = scalef[0];
#pragma unroll
    for (int i = 0; i < 4; i++) {
        int row = base + rg * 4 + i;
        if (row < N) {
            float4 o;
            o.x = (acc[i][0] + bb.x) * sf;
            o.y = (acc[i][1] + bb.y) * sf;
            o.z = (acc[i][2] + bb.z) * sf;
            o.w = (acc[i][3] + bb.w) * sf;
            ((float4*)(out + (size_t)row * 64))[cg] = o;
        }
    }
}

extern "C" void kernel_launch(void* const* d_in, const int* in_sizes, int n_in,
                              void* d_out, int out_size, void* d_ws, size_t ws_size,
                              hipStream_t stream) {
    const float* x  = (const float*)d_in[0];
    const int*   ei = (const int*)d_in[1];
    const float* Wq = (const float*)d_in[2];
    const float* bq = (const float*)d_in[3];
    const float* Wk = (const float*)d_in[4];
    const float* bk = (const float*)d_in[5];
    const float* Wv = (const float*)d_in[6];
    const float* bv = (const float*)d_in[7];
    const float* Wo = (const float*)d_in[8];
    const float* bo = (const float*)d_in[9];
    float* out = (float*)d_out;

    const int N = in_sizes[0] / 128;   // 100000
    const int E = in_sizes[1] / 2;
    const size_t NR = (size_t)N * 128;
    const int NGB = (N + 127) / 128;   // 782 GEMM blocks (128 rows each)
    const int HBn = (NGB + 1) / 2;     // 391 interleaved histogram blocks
    const int NB64 = (N + 63) / 64;    // 1563 blocks for k_out2
    const int GB = (N + 7) / 8;        // 12500 edge-kernel blocks
    const int T = (N + 1023) / 1024;

    float* qn = (float*)d_ws;          // N*128 ; reused as U after k_edge
    float* kv = qn + NR;               // N*256 (k|v interleaved per node)
    int* counts = (int*)(kv + NR * 2);         // N
    int* offs   = counts + N;                  // N+2
    int* cursor = offs + N + 2;                // N
    int* ccol   = cursor + N;                  // E
    double* psum = (double*)(ccol + E);        // GB*2 partial expsums
    int* tsum   = (int*)(psum + (size_t)GB * 2);  // T scan tiles
    double* sumf = (double*)(tsum + T + (T & 1)); // 2 doubles (8B aligned)
    float* scalef = (float*)(sumf + 2);           // 1

    // packed W hi/lo fragments live in ccol's space (consumed before k_fill writes)
    uintptr_t pw = ((uintptr_t)ccol + 15) & ~(uintptr_t)15;
    half8* whi = (half8*)pw;                   // 6144 * 16B
    half8* wlo = whi + 6144;                   // 6144 * 16B
    float* w127 = (float*)(wlo + 6144);        // 3*128 floats

    float* U = qn;  // aggregation output aliases q (per-n read-then-write)

    hipMemsetAsync(counts, 0, (size_t)N * sizeof(int), stream);
    k_wpack<<<24, 256, 0, stream>>>(Wq, Wk, Wv, whi, wlo, w127);
    k_qkvm<<<NGB + HBn, 256, 0, stream>>>(x, whi, wlo, w127, bq, bk, bv,
                                          qn, kv, ei, counts, N, E);
    k_scan1<<<T, 256, 0, stream>>>(counts, offs, tsum, N);
    k_scan2<<<1, 64, 0, stream>>>(tsum, offs, T, N);
    k_scan3<<<(N + 255) / 256, 256, 0, stream>>>(offs, cursor, tsum, N);
    k_fill<<<1024, 256, 0, stream>>>(ei, cursor, ccol, E);
    k_edge<<<GB, 256, 0, stream>>>(qn, kv, offs, ccol, U, psum, N);
    k_sum2<<<1, 256, 0, stream>>>(psum, sumf, GB);
    k_crout4<<<1, 256, 0, stream>>>(x, U, Wo, bo, sumf, scalef);
    k_out2<<<NB64, 256, 0, stream>>>(U, Wo, bo, sumf, scalef, out, N);
}

// Round 4
// 477.402 us; speedup vs baseline: 1.2529x; 1.0401x over previous
//
#include <hip/hip_runtime.h>
#include <math.h>

#define EPSF 1e-9f
#define INV_SQRT128 0.08838834764831845f

typedef _Float16 half8 __attribute__((ext_vector_type(8)));
typedef float f32x4 __attribute__((ext_vector_type(4)));

// async global->LDS, 16B per lane: lane l reads g[l], HW writes lds_base + l*16
__device__ __forceinline__ void gl_lds16(const void* g, void* l) {
    __builtin_amdgcn_global_load_lds((const __attribute__((address_space(1))) void*)g,
                                     (__attribute__((address_space(3))) void*)l, 16, 0, 0);
}

// ---------------- W pre-pack: fp32 -> (hi fp16, lo fp16*4096) MFMA B-fragments ----------
// half8 slot t = ((kind*4+ks)*4+g)*128 + col  holds W[kind][col][ks*32+g*8 .. +8].
__global__ void k_wpack(const float* __restrict__ Wq, const float* __restrict__ Wk,
                        const float* __restrict__ Wv, half8* __restrict__ whi,
                        half8* __restrict__ wlo, float* __restrict__ w127) {
    int t = blockIdx.x * 256 + threadIdx.x;   // 6144 items
    if (t >= 6144) return;
    int col = t & 127, g = (t >> 7) & 3, ks = (t >> 9) & 3, kind = t >> 11;
    const float* W = (kind == 0) ? Wq : (kind == 1) ? Wk : Wv;
    const float4* W4 = (const float4*)W;
    float4 a = W4[col * 32 + ks * 8 + g * 2];
    float4 b = W4[col * 32 + ks * 8 + g * 2 + 1];
    float xv[8] = {a.x, a.y, a.z, a.w, b.x, b.y, b.z, b.w};
    half8 h, lo;
#pragma unroll
    for (int j = 0; j < 8; j++) {
        _Float16 hh = (_Float16)xv[j];
        h[j] = hh;
        lo[j] = (_Float16)((xv[j] - (float)hh) * 4096.0f);
    }
    whi[t] = h;
    wlo[t] = lo;
    if (ks == 3 && g == 3) w127[kind * 128 + col] = xv[7];   // W[col][127]
}

// ---------------- Wo pre-pack (for k_outm): slot t=(ks*4+g)*64+col, Wo[col][ks*32+g*8..+8]
__global__ void k_wpack2(const float* __restrict__ Wo, half8* __restrict__ wohi,
                         half8* __restrict__ wolo) {
    int t = blockIdx.x * 256 + threadIdx.x;   // 1024 items
    if (t >= 1024) return;
    int col = t & 63, g = (t >> 6) & 3, ks = t >> 8;
    const float4* W4 = (const float4*)Wo;
    float4 a = W4[col * 32 + ks * 8 + g * 2];
    float4 b = W4[col * 32 + ks * 8 + g * 2 + 1];
    float xv[8] = {a.x, a.y, a.z, a.w, b.x, b.y, b.z, b.w};
    half8 h, lo;
#pragma unroll
    for (int j = 0; j < 8; j++) {
        _Float16 hh = (_Float16)xv[j];
        h[j] = hh;
        lo[j] = (_Float16)((xv[j] - (float)hh) * 4096.0f);
    }
    wohi[t] = h;
    wolo[t] = lo;
}

// ---------------- fused qkv via split-fp16 MFMA, B staged in LDS ----------------
// 256 thr = 4 waves x 32 rows = 128 rows/block. Histogram blocks interleaved 1-in-3.
__global__ void __launch_bounds__(256, 2)
k_qkvm(const float* __restrict__ x,
       const half8* __restrict__ whi, const half8* __restrict__ wlo,
       const float* __restrict__ w127,
       const float* __restrict__ bq, const float* __restrict__ bk,
       const float* __restrict__ bv,
       float* __restrict__ qn, float* __restrict__ kvout,
       const int* __restrict__ ei, int* __restrict__ counts,
       int N, int E) {
    int b = (int)blockIdx.x;
    if (b % 3 == 2) {                 // histogram role, interleaved
        int HB = (int)gridDim.x / 3;
        int stride = HB * 256;
        for (int e = (b / 3) * 256 + (int)threadIdx.x; e < E; e += stride)
            atomicAdd(&counts[ei[e]], 1);
        return;
    }
    int gb = b - (b + 1) / 3;         // GEMM block id

    __shared__ half8 bsh[4096];       // 64 KB: [0..2048) hi, [2048..4096) lo

    int tid = threadIdx.x;
    int wv = tid >> 6;                // wave 0..3
    int l = tid & 63;
    int r = l & 15;                   // A-row / out-col lane index
    int g = l >> 4;                   // k-group / out-row group
    int rowbase = gb * 128 + wv * 32;
    const float4* x4 = (const float4*)x;

    // ---- issue kind-0 B staging first (latency overlaps x processing) ----
    {
        const half8* sH = whi + wv * 512;
        const half8* sL = wlo + wv * 512;
#pragma unroll
        for (int i = 0; i < 8; i++) {
            gl_lds16(sH + i * 64 + l, bsh + wv * 512 + i * 64);
            gl_lds16(sL + i * 64 + l, bsh + 2048 + wv * 512 + i * 64);
        }
    }

    // ---- load x for 2 row-tiles, build hi/lo frags, fold normalization ----
    half8 hiA[2][4], loA[2][4];
    float rnj[2][4], tcj[2][4];
#pragma unroll
    for (int t = 0; t < 2; t++) {
        int row = min(rowbase + t * 16 + r, N - 1);
        float ssum = 0.f, tl = 0.f;
#pragma unroll
        for (int ks = 0; ks < 4; ks++) {
            float4 a = x4[(size_t)row * 32 + ks * 8 + g * 2];
            float4 bb = x4[(size_t)row * 32 + ks * 8 + g * 2 + 1];
            float xv[8] = {a.x, a.y, a.z, a.w, bb.x, bb.y, bb.z, bb.w};
#pragma unroll
            for (int j = 0; j < 8; j++) {
                _Float16 hh = (_Float16)xv[j];
                hiA[t][ks][j] = hh;
                loA[t][ks][j] = (_Float16)((xv[j] - (float)hh) * 4096.0f);
                ssum += xv[j] * xv[j];
            }
            if (ks == 3 && g == 3) { tl = xv[7]; ssum -= xv[7] * xv[7]; }
        }
        ssum += __shfl_xor(ssum, 16);
        ssum += __shfl_xor(ssum, 32);
        float rn = 1.f / fmaxf(sqrtf(ssum), EPSF);
        float tla = __shfl(tl, 48 + r);        // x127 of row (t, r)
        float tc = tla * (1.f - rn);
#pragma unroll
        for (int j = 0; j < 4; j++) {
            rnj[t][j] = __shfl(rn, g * 4 + j);
            tcj[t][j] = __shfl(tc, g * 4 + j);
        }
    }

    asm volatile("s_waitcnt vmcnt(0)" ::: "memory");
    __syncthreads();                  // kind-0 B resident in LDS

    const float* const bks[3] = {bq, bk, bv};
    bool lane15 = (r == 15);
    const f32x4 zz = {0.f, 0.f, 0.f, 0.f};
    int dsbase = g * 128 + r;         // half8-slot base for this lane

    for (int kind = 0; kind < 3; kind++) {
        // per-kind epilogue constants (issued early, overlap MFMA phase)
        float wcA[2][4], bbA[2][4];
#pragma unroll
        for (int h = 0; h < 2; h++)
#pragma unroll
            for (int ct = 0; ct < 4; ct++) {
                int col = (h * 4 + ct) * 16 + r;
                wcA[h][ct] = w127[kind * 128 + col];
                bbA[h][ct] = bks[kind][col];
            }

#pragma unroll
        for (int h = 0; h < 2; h++) {
            f32x4 aM[2][4], aX[2][4];
#pragma unroll
            for (int t = 0; t < 2; t++)
#pragma unroll
                for (int ct = 0; ct < 4; ct++) { aM[t][ct] = zz; aX[t][ct] = zz; }

#pragma unroll
            for (int ks = 0; ks < 4; ks++) {
                half8 hB[4], lB[4];
#pragma unroll
                for (int ct = 0; ct < 4; ct++) {
                    int bi = dsbase + ks * 512 + (h * 4 + ct) * 16;
                    hB[ct] = bsh[bi];
                    lB[ct] = bsh[2048 + bi];
                }
#pragma unroll
                for (int ct = 0; ct < 4; ct++) {
                    aM[0][ct] = __builtin_amdgcn_mfma_f32_16x16x32_f16(hiA[0][ks], hB[ct], aM[0][ct], 0, 0, 0);
                    aM[1][ct] = __builtin_amdgcn_mfma_f32_16x16x32_f16(hiA[1][ks], hB[ct], aM[1][ct], 0, 0, 0);
                    aX[0][ct] = __builtin_amdgcn_mfma_f32_16x16x32_f16(hiA[0][ks], lB[ct], aX[0][ct], 0, 0, 0);
                    aX[0][ct] = __builtin_amdgcn_mfma_f32_16x16x32_f16(loA[0][ks], hB[ct], aX[0][ct], 0, 0, 0);
                    aX[1][ct] = __builtin_amdgcn_mfma_f32_16x16x32_f16(hiA[1][ks], lB[ct], aX[1][ct], 0, 0, 0);
                    aX[1][ct] = __builtin_amdgcn_mfma_f32_16x16x32_f16(loA[1][ks], hB[ct], aX[1][ct], 0, 0, 0);
                }
            }

            // epilogue for head h: combine, norm-correct, q/k head-normalize, store
#pragma unroll
            for (int t = 0; t < 2; t++) {
                float cv[4][4];       // [ct][j]
#pragma unroll
                for (int ct = 0; ct < 4; ct++)
#pragma unroll
                    for (int j = 0; j < 4; j++) {
                        float acc = aM[t][ct][j] + aX[t][ct][j] * (1.0f / 4096.0f);
                        cv[ct][j] = fmaf(rnj[t][j], acc, fmaf(tcj[t][j], wcA[h][ct], bbA[h][ct]));
                    }
                if (kind < 2) {
#pragma unroll
                    for (int j = 0; j < 4; j++) {
                        float ss = 0.f;
#pragma unroll
                        for (int ct = 0; ct < 4; ct++) {
                            float c = cv[ct][j];
                            ss += (ct == 3 && lane15) ? 0.f : c * c;
                        }
                        ss += __shfl_xor(ss, 1);
                        ss += __shfl_xor(ss, 2);
                        ss += __shfl_xor(ss, 4);
                        ss += __shfl_xor(ss, 8);
                        float rh = 1.f / fmaxf(sqrtf(ss), EPSF);
#pragma unroll
                        for (int ct = 0; ct < 4; ct++) {
                            bool ist = (ct == 3) && lane15;
                            if (!ist) cv[ct][j] *= rh;
                            if (kind == 0) {
                                if (ist) cv[ct][j] = -cv[ct][j];
                                cv[ct][j] *= INV_SQRT128;
                            }
                        }
                    }
                }
#pragma unroll
                for (int j = 0; j < 4; j++) {
                    int row = rowbase + t * 16 + g * 4 + j;
                    if (row < N) {
                        float* dst = (kind == 0)
                            ? (qn + (size_t)row * 128)
                            : (kvout + (size_t)row * 256 + (kind == 2 ? 128 : 0));
#pragma unroll
                        for (int ct = 0; ct < 4; ct++)
                            dst[(h * 4 + ct) * 16 + r] = cv[ct][j];
                    }
                }
            }
        }

        if (kind < 2) {               // restage B for next kind
            __syncthreads();          // all waves done reading bsh
            const half8* sH = whi + (kind + 1) * 2048 + wv * 512;
            const half8* sL = wlo + (kind + 1) * 2048 + wv * 512;
#pragma unroll
            for (int i = 0; i < 8; i++) {
                gl_lds16(sH + i * 64 + l, bsh + wv * 512 + i * 64);
                gl_lds16(sL + i * 64 + l, bsh + 2048 + wv * 512 + i * 64);
            }
            asm volatile("s_waitcnt vmcnt(0)" ::: "memory");
            __syncthreads();
        }
    }
}

// ---------------- CSR build (scan + fill) ----------------
__global__ void k_scan1(const int* __restrict__ counts, int* __restrict__ offs,
                        int* __restrict__ tsum, int N) {
    __shared__ int sd[256];
    int tile = blockIdx.x;
    int t = threadIdx.x;
    int i0 = tile * 1024 + t * 4;
    int v[4];
    int lsum = 0;
    for (int j = 0; j < 4; j++) {
        int idx = i0 + j;
        v[j] = (idx < N) ? counts[idx] : 0;
        lsum += v[j];
    }
    sd[t] = lsum;
    __syncthreads();
    for (int off = 1; off < 256; off <<= 1) {
        int val = sd[t];
        int add = (t >= off) ? sd[t - off] : 0;
        __syncthreads();
        sd[t] = val + add;
        __syncthreads();
    }
    int excl = (t == 0) ? 0 : sd[t - 1];
    if (t == 255) tsum[tile] = sd[255];
    int run = excl;
    for (int j = 0; j < 4; j++) {
        int idx = i0 + j;
        if (idx < N) offs[idx] = run;
        run += v[j];
    }
}

__global__ void k_scan2(int* __restrict__ tsum, int* __restrict__ offs, int T, int N) {
    if (threadIdx.x == 0) {
        int run = 0;
        for (int i = 0; i < T; i++) {
            int t = tsum[i];
            tsum[i] = run;
            run += t;
        }
        offs[N] = run;
    }
}

__global__ void k_scan3(int* __restrict__ offs, int* __restrict__ cursor,
                        const int* __restrict__ tsum, int N) {
    int i = blockIdx.x * blockDim.x + threadIdx.x;
    if (i < N) {
        int o = offs[i] + tsum[i >> 10];
        offs[i] = o;
        cursor[i] = o;
    }
}

// stores the COLUMN id in CSR order
__global__ void k_fill(const int* __restrict__ ei, int* __restrict__ cursor,
                       int* __restrict__ ccol, int E) {
    int stride = blockDim.x * gridDim.x;
    for (int e = blockIdx.x * blockDim.x + threadIdx.x; e < E; e += stride) {
        int r = ei[e];
        int p = atomicAdd(&cursor[r], 1);
        ccol[p] = ei[E + e];
    }
}

// ---------------- fused edge pass: scores + exp + aggregate (unnormalized) ----------------
// Round-4: unroll-4 with all 8 gathers batched up front (round-3 was MLP-bound:
// HBM 46%, VALU 25%, occupancy 78% -> per-wave outstanding-load depth was the limit).
__global__ void k_edge(const float* __restrict__ qn, const float* __restrict__ kv,
                       const int* __restrict__ offs, const int* __restrict__ ccol,
                       float* __restrict__ U, double* __restrict__ psum, int N) {
    int g = threadIdx.x >> 5;            // 8 groups of 32 lanes
    int l = threadIdx.x & 31;
    int head = l >> 4;
    int n = blockIdx.x * 8 + g;
    double esum = 0.0;
    if (n < N) {
        float4 q4 = ((const float4*)qn)[(size_t)n * 32 + l];
        int s0 = offs[n], s1 = offs[n + 1];
        float4 acc = {0.f, 0.f, 0.f, 0.f};
        const float4* kv4 = (const float4*)kv;
        int i = s0;
        for (; i + 4 <= s1; i += 4) {
            int c0 = ccol[i];
            int c1 = ccol[i + 1];
            int c2 = ccol[i + 2];
            int c3 = ccol[i + 3];
            float4 ka = kv4[(size_t)c0 * 64 + l];
            float4 va = kv4[(size_t)c0 * 64 + 32 + l];
            float4 kb = kv4[(size_t)c1 * 64 + l];
            float4 vb = kv4[(size_t)c1 * 64 + 32 + l];
            float4 kc = kv4[(size_t)c2 * 64 + l];
            float4 vc = kv4[(size_t)c2 * 64 + 32 + l];
            float4 kd = kv4[(size_t)c3 * 64 + l];
            float4 vd = kv4[(size_t)c3 * 64 + 32 + l];
            float p0 = q4.x * ka.x;
            p0 = fmaf(q4.y, ka.y, p0); p0 = fmaf(q4.z, ka.z, p0); p0 = fmaf(q4.w, ka.w, p0);
            float p1 = q4.x * kb.x;
            p1 = fmaf(q4.y, kb.y, p1); p1 = fmaf(q4.z, kb.z, p1); p1 = fmaf(q4.w, kb.w, p1);
            float p2 = q4.x * kc.x;
            p2 = fmaf(q4.y, kc.y, p2); p2 = fmaf(q4.z, kc.z, p2); p2 = fmaf(q4.w, kc.w, p2);
            float p3 = q4.x * kd.x;
            p3 = fmaf(q4.y, kd.y, p3); p3 = fmaf(q4.z, kd.z, p3); p3 = fmaf(q4.w, kd.w, p3);
            p0 += __shfl_xor(p0, 1); p1 += __shfl_xor(p1, 1);
            p2 += __shfl_xor(p2, 1); p3 += __shfl_xor(p3, 1);
            p0 += __shfl_xor(p0, 2); p1 += __shfl_xor(p1, 2);
            p2 += __shfl_xor(p2, 2); p3 += __shfl_xor(p3, 2);
            p0 += __shfl_xor(p0, 4); p1 += __shfl_xor(p1, 4);
            p2 += __shfl_xor(p2, 4); p3 += __shfl_xor(p3, 4);
            p0 += __shfl_xor(p0, 8); p1 += __shfl_xor(p1, 8);
            p2 += __shfl_xor(p2, 8); p3 += __shfl_xor(p3, 8);
            float e0 = expf(p0);
            float e1 = expf(p1);
            float e2 = expf(p2);
            float e3 = expf(p3);
            acc.x = fmaf(va.x, e0, acc.x); acc.y = fmaf(va.y, e0, acc.y);
            acc.z = fmaf(va.z, e0, acc.z); acc.w = fmaf(va.w, e0, acc.w);
            acc.x = fmaf(vb.x, e1, acc.x); acc.y = fmaf(vb.y, e1, acc.y);
            acc.z = fmaf(vb.z, e1, acc.z); acc.w = fmaf(vb.w, e1, acc.w);
            acc.x = fmaf(vc.x, e2, acc.x); acc.y = fmaf(vc.y, e2, acc.y);
            acc.z = fmaf(vc.z, e2, acc.z); acc.w = fmaf(vc.w, e2, acc.w);
            acc.x = fmaf(vd.x, e3, acc.x); acc.y = fmaf(vd.y, e3, acc.y);
            acc.z = fmaf(vd.z, e3, acc.z); acc.w = fmaf(vd.w, e3, acc.w);
            esum += (double)((e0 + e1) + (e2 + e3));
        }
        for (; i < s1; i++) {
            int c = ccol[i];
            float4 k4 = kv4[(size_t)c * 64 + l];
            float4 v4 = kv4[(size_t)c * 64 + 32 + l];
            float p = q4.x * k4.x;
            p = fmaf(q4.y, k4.y, p); p = fmaf(q4.z, k4.z, p); p = fmaf(q4.w, k4.w, p);
            p += __shfl_xor(p, 1);
            p += __shfl_xor(p, 2);
            p += __shfl_xor(p, 4);
            p += __shfl_xor(p, 8);
            float e = expf(p);
            acc.x = fmaf(v4.x, e, acc.x); acc.y = fmaf(v4.y, e, acc.y);
            acc.z = fmaf(v4.z, e, acc.z); acc.w = fmaf(v4.w, e, acc.w);
            esum += (double)e;
        }
        ((float4*)U)[(size_t)n * 32 + l] = acc;
    }
    __shared__ double sd[2][8];
    if ((l & 15) == 0) sd[head][g] = esum;
    __syncthreads();
    if (threadIdx.x < 2) {
        double s = 0.0;
        for (int i2 = 0; i2 < 8; i2++) s += sd[threadIdx.x][i2];
        psum[(size_t)blockIdx.x * 2 + threadIdx.x] = s;
    }
}

// deterministic reduce of per-block partials -> sumf[2] (double)
__global__ void k_sum2(const double* __restrict__ psum, double* __restrict__ sumf, int P) {
    double s0 = 0.0, s1 = 0.0;
    for (int i = threadIdx.x; i < P; i += blockDim.x) {
        s0 += psum[2 * i];
        s1 += psum[2 * i + 1];
    }
    for (int off = 32; off; off >>= 1) {
        s0 += __shfl_xor(s0, off);
        s1 += __shfl_xor(s1, off);
    }
    __shared__ double sd[2][4];
    int w = threadIdx.x >> 6;
    if ((threadIdx.x & 63) == 0) { sd[0][w] = s0; sd[1][w] = s1; }
    __syncthreads();
    if (threadIdx.x == 0) {
        for (int i = 1; i < 4; i++) { s0 += sd[0][i]; s1 += sd[1][i]; }
        sumf[0] = s0;
        sumf[1] = s1;
    }
}

// ---------------- cr_initial (from x) + rows 0-3 of out + scale factor ----------------
__global__ void k_crout4(const float* __restrict__ x, const float* __restrict__ U,
                         const float* __restrict__ Wo, const float* __restrict__ bo,
                         const double* __restrict__ sumf, float* __restrict__ scalef) {
    __shared__ float xs[4 * 128];
    __shared__ float o4[4 * 64];
    __shared__ double crin_sh;
    int tid = threadIdx.x;  // 256
    xs[tid] = U[tid];
    xs[tid + 256] = U[tid + 256];
    if (tid < 64) {         // wave 0: cross-ratio of raw x rows 0..3
        int l = tid;
        const int pa[4] = {0, 1, 0, 1};
        const int pb[4] = {2, 3, 3, 2};
        double inner[4];
        for (int p = 0; p < 4; p++) {
            const float* a = x + pa[p] * 128;
            const float* b = x + pb[p] * 128;
            double s = (double)a[l] * (double)b[l];
            double t = (double)a[l + 64] * (double)b[l + 64];
            s += (l == 63) ? -t : t;
            for (int off = 32; off; off >>= 1) s += __shfl_xor(s, off);
            inner[p] = s;
        }
        if (l == 0) {
            double num = inner[0] * inner[1];
            double den = inner[2] * inner[3];
            if (fabs(den) < 1e-9) den = 1e-9;
            crin_sh = num / den;
        }
    }
    __syncthreads();
    int w = tid >> 6, o = tid & 63;
    float si0 = (float)(1.0 / sumf[0]);
    float si1 = (float)(1.0 / sumf[1]);
    const float* xr = xs + w * 128;
    const float* wr = Wo + (size_t)o * 128;
    float d0 = 0.f, d1 = 0.f;
    for (int j = 0; j < 64; j++) d0 = fmaf(xr[j], wr[j], d0);
    for (int j = 64; j < 128; j++) d1 = fmaf(xr[j], wr[j], d1);
    o4[w * 64 + o] = d0 * si0 + d1 * si1 + bo[o];
    __syncthreads();
    if (tid < 64) {
        int l = tid;
        const int pa[4] = {0, 1, 0, 1};
        const int pb[4] = {2, 3, 3, 2};
        double inner[4];
        for (int p = 0; p < 4; p++) {
            double t = (double)o4[pa[p] * 64 + l] * (double)o4[pb[p] * 64 + l];
            if (l == 63) t = -t;
            for (int off = 32; off; off >>= 1) t += __shfl_xor(t, off);
            inner[p] = t;
        }
        if (l == 0) {
            double num = inner[0] * inner[1];
            double den = inner[2] * inner[3];
            if (fabs(den) < 1e-9) den = 1e-9;
            double crc = num / den;
            if (fabs(crc) < 1e-9) crc = 1e-9;
            double ratio = crin_sh / crc;
            scalef[0] = (float)pow(fabs(ratio), 0.25);
        }
    }
}

// ---------------- final GEMM via split-fp16 MFMA: out = ((U/sumf)@Wo.T + bo)*scalef ----
// 256 thr = 4 waves x 32 rows = 128 rows/block. Wo hi/lo frags staged once to LDS (32 KB).
__global__ void __launch_bounds__(256, 2)
k_outm(const float* __restrict__ U, const half8* __restrict__ wohi,
       const half8* __restrict__ wolo, const float* __restrict__ bo,
       const double* __restrict__ sumf, const float* __restrict__ scalef,
       float* __restrict__ out, int N) {
    __shared__ half8 bsh[2048];       // 32 KB: [0..1024) hi, [1024..2048) lo
    int tid = threadIdx.x;
    int wv = tid >> 6;                // wave 0..3
    int l = tid & 63;
    int r = l & 15;                   // A-row / out-col lane index
    int g = l >> 4;                   // k-group / out-row group
    int rowbase = blockIdx.x * 128 + wv * 32;

    {   // stage Wo frags (each wave stages 256 hi + 256 lo slots)
        const half8* sH = wohi + wv * 256;
        const half8* sL = wolo + wv * 256;
#pragma unroll
        for (int i = 0; i < 4; i++) {
            gl_lds16(sH + i * 64 + l, bsh + wv * 256 + i * 64);
            gl_lds16(sL + i * 64 + l, bsh + 1024 + wv * 256 + i * 64);
        }
    }

    float si0 = (float)(1.0 / sumf[0]);
    float si1 = (float)(1.0 / sumf[1]);
    const float4* U4 = (const float4*)U;
    half8 hiA[2][4], loA[2][4];
#pragma unroll
    for (int t = 0; t < 2; t++) {
        int row = min(rowbase + t * 16 + r, N - 1);
#pragma unroll
        for (int ks = 0; ks < 4; ks++) {
            float si = (ks < 2) ? si0 : si1;
            float4 a = U4[(size_t)row * 32 + ks * 8 + g * 2];
            float4 b = U4[(size_t)row * 32 + ks * 8 + g * 2 + 1];
            float xv[8] = {a.x, a.y, a.z, a.w, b.x, b.y, b.z, b.w};
#pragma unroll
            for (int j = 0; j < 8; j++) {
                float v = xv[j] * si;
                _Float16 hh = (_Float16)v;
                hiA[t][ks][j] = hh;
                loA[t][ks][j] = (_Float16)((v - (float)hh) * 4096.0f);
            }
        }
    }

    asm volatile("s_waitcnt vmcnt(0)" ::: "memory");
    __syncthreads();

    const f32x4 zz = {0.f, 0.f, 0.f, 0.f};
    f32x4 aM[2][4], aX[2][4];
#pragma unroll
    for (int t = 0; t < 2; t++)
#pragma unroll
        for (int ct = 0; ct < 4; ct++) { aM[t][ct] = zz; aX[t][ct] = zz; }

#pragma unroll
    for (int ks = 0; ks < 4; ks++) {
        half8 hB[4], lB[4];
#pragma unroll
        for (int ct = 0; ct < 4; ct++) {
            int bi = ks * 256 + g * 64 + ct * 16 + r;
            hB[ct] = bsh[bi];
            lB[ct] = bsh[1024 + bi];
        }
#pragma unroll
        for (int ct = 0; ct < 4; ct++) {
            aM[0][ct] = __builtin_amdgcn_mfma_f32_16x16x32_f16(hiA[0][ks], hB[ct], aM[0][ct], 0, 0, 0);
            aM[1][ct] = __builtin_amdgcn_mfma_f32_16x16x32_f16(hiA[1][ks], hB[ct], aM[1][ct], 0, 0, 0);
            aX[0][ct] = __builtin_amdgcn_mfma_f32_16x16x32_f16(hiA[0][ks], lB[ct], aX[0][ct], 0, 0, 0);
            aX[0][ct] = __builtin_amdgcn_mfma_f32_16x16x32_f16(loA[0][ks], hB[ct], aX[0][ct], 0, 0, 0);
            aX[1][ct] = __builtin_amdgcn_mfma_f32_16x16x32_f16(hiA[1][ks], lB[ct], aX[1][ct], 0, 0, 0);
            aX[1][ct] = __builtin_amdgcn_mfma_f32_16x16x32_f16(loA[1][ks], hB[ct], aX[1][ct], 0, 0, 0);
        }
    }

    float sf = scalef[0];
#pragma unroll
    for (int t = 0; t < 2; t++)
#pragma unroll
        for (int ct = 0; ct < 4; ct++) {
            float bb = bo[ct * 16 + r];
#pragma unroll
            for (int j = 0; j < 4; j++) {
                int row = rowbase + t * 16 + g * 4 + j;
                if (row < N) {
                    float c = (aM[t][ct][j] + aX[t][ct][j] * (1.0f / 4096.0f) + bb) * sf;
                    out[(size_t)row * 64 + ct * 16 + r] = c;
                }
            }
        }
}

extern "C" void kernel_launch(void* const* d_in, const int* in_sizes, int n_in,
                              void* d_out, int out_size, void* d_ws, size_t ws_size,
                              hipStream_t stream) {
    const float* x  = (const float*)d_in[0];
    const int*   ei = (const int*)d_in[1];
    const float* Wq = (const float*)d_in[2];
    const float* bq = (const float*)d_in[3];
    const float* Wk = (const float*)d_in[4];
    const float* bk = (const float*)d_in[5];
    const float* Wv = (const float*)d_in[6];
    const float* bv = (const float*)d_in[7];
    const float* Wo = (const float*)d_in[8];
    const float* bo = (const float*)d_in[9];
    float* out = (float*)d_out;

    const int N = in_sizes[0] / 128;   // 100000
    const int E = in_sizes[1] / 2;
    const size_t NR = (size_t)N * 128;
    const int NGB = (N + 127) / 128;   // 782 GEMM blocks (128 rows each)
    const int HBn = (NGB + 1) / 2;     // 391 interleaved histogram blocks
    const int GB = (N + 7) / 8;        // 12500 edge-kernel blocks
    const int T = (N + 1023) / 1024;

    float* qn = (float*)d_ws;          // N*128 ; reused as U after k_edge
    float* kv = qn + NR;               // N*256 (k|v interleaved per node)
    int* counts = (int*)(kv + NR * 2);         // N
    int* offs   = counts + N;                  // N+2
    int* cursor = offs + N + 2;                // N
    int* ccol   = cursor + N;                  // E
    double* psum = (double*)(ccol + E);        // GB*2 partial expsums
    int* tsum   = (int*)(psum + (size_t)GB * 2);  // T scan tiles
    double* sumf = (double*)(tsum + T + (T & 1)); // 2 doubles (8B aligned)
    float* scalef = (float*)(sumf + 2);           // 1

    // packed Wq/Wk/Wv hi/lo frags live in ccol's space (consumed before k_fill writes)
    uintptr_t pw = ((uintptr_t)ccol + 15) & ~(uintptr_t)15;
    half8* whi = (half8*)pw;                   // 6144 * 16B
    half8* wlo = whi + 6144;                   // 6144 * 16B
    float* w127 = (float*)(wlo + 6144);        // 3*128 floats

    // packed Wo frags live in counts' space (counts dead after k_scan1)
    uintptr_t pw2 = ((uintptr_t)counts + 15) & ~(uintptr_t)15;
    half8* wohi = (half8*)pw2;                 // 1024 * 16B
    half8* wolo = wohi + 1024;                 // 1024 * 16B

    float* U = qn;  // aggregation output aliases q (per-n read-then-write)

    hipMemsetAsync(counts, 0, (size_t)N * sizeof(int), stream);
    k_wpack<<<24, 256, 0, stream>>>(Wq, Wk, Wv, whi, wlo, w127);
    k_qkvm<<<NGB + HBn, 256, 0, stream>>>(x, whi, wlo, w127, bq, bk, bv,
                                          qn, kv, ei, counts, N, E);
    k_scan1<<<T, 256, 0, stream>>>(counts, offs, tsum, N);
    k_wpack2<<<4, 256, 0, stream>>>(Wo, wohi, wolo);   // counts space now dead
    k_scan2<<<1, 64, 0, stream>>>(tsum, offs, T, N);
    k_scan3<<<(N + 255) / 256, 256, 0, stream>>>(offs, cursor, tsum, N);
    k_fill<<<1024, 256, 0, stream>>>(ei, cursor, ccol, E);
    k_edge<<<GB, 256, 0, stream>>>(qn, kv, offs, ccol, U, psum, N);
    k_sum2<<<1, 256, 0, stream>>>(psum, sumf, GB);
    k_crout4<<<1, 256, 0, stream>>>(x, U, Wo, bo, sumf, scalef);
    k_outm<<<NGB, 256, 0, stream>>>(U, wohi, wolo, bo, sumf, scalef, out, N);
}

// Round 5
// 413.258 us; speedup vs baseline: 1.4473x; 1.1552x over previous
//
#include <hip/hip_runtime.h>
#include <math.h>

#define EPSF 1e-9f
#define INV_SQRT128 0.08838834764831845f

typedef _Float16 half8 __attribute__((ext_vector_type(8)));
typedef float f32x4 __attribute__((ext_vector_type(4)));

// async global->LDS, 16B per lane: lane l reads g[l], HW writes lds_base + l*16
__device__ __forceinline__ void gl_lds16(const void* g, void* l) {
    __builtin_amdgcn_global_load_lds((const __attribute__((address_space(1))) void*)g,
                                     (__attribute__((address_space(3))) void*)l, 16, 0, 0);
}

// ---------------- W pre-pack: fp32 -> (hi fp16, lo fp16*4096) MFMA B-fragments ----------
// half8 slot t = ((kind*4+ks)*4+g)*128 + col  holds W[kind][col][ks*32+g*8 .. +8].
__global__ void k_wpack(const float* __restrict__ Wq, const float* __restrict__ Wk,
                        const float* __restrict__ Wv, half8* __restrict__ whi,
                        half8* __restrict__ wlo, float* __restrict__ w127) {
    int t = blockIdx.x * 256 + threadIdx.x;   // 6144 items
    if (t >= 6144) return;
    int col = t & 127, g = (t >> 7) & 3, ks = (t >> 9) & 3, kind = t >> 11;
    const float* W = (kind == 0) ? Wq : (kind == 1) ? Wk : Wv;
    const float4* W4 = (const float4*)W;
    float4 a = W4[col * 32 + ks * 8 + g * 2];
    float4 b = W4[col * 32 + ks * 8 + g * 2 + 1];
    float xv[8] = {a.x, a.y, a.z, a.w, b.x, b.y, b.z, b.w};
    half8 h, lo;
#pragma unroll
    for (int j = 0; j < 8; j++) {
        _Float16 hh = (_Float16)xv[j];
        h[j] = hh;
        lo[j] = (_Float16)((xv[j] - (float)hh) * 4096.0f);
    }
    whi[t] = h;
    wlo[t] = lo;
    if (ks == 3 && g == 3) w127[kind * 128 + col] = xv[7];   // W[col][127]
}

// ---------------- Wo pre-pack (for k_outm): slot t=(ks*4+g)*64+col ----------
__global__ void k_wpack2(const float* __restrict__ Wo, half8* __restrict__ wohi,
                         half8* __restrict__ wolo) {
    int t = blockIdx.x * 256 + threadIdx.x;   // 1024 items
    if (t >= 1024) return;
    int col = t & 63, g = (t >> 6) & 3, ks = t >> 8;
    const float4* W4 = (const float4*)Wo;
    float4 a = W4[col * 32 + ks * 8 + g * 2];
    float4 b = W4[col * 32 + ks * 8 + g * 2 + 1];
    float xv[8] = {a.x, a.y, a.z, a.w, b.x, b.y, b.z, b.w};
    half8 h, lo;
#pragma unroll
    for (int j = 0; j < 8; j++) {
        _Float16 hh = (_Float16)xv[j];
        h[j] = hh;
        lo[j] = (_Float16)((xv[j] - (float)hh) * 4096.0f);
    }
    wohi[t] = h;
    wolo[t] = lo;
}

// ---------------- fused qkv via split-fp16 MFMA, B staged in LDS (pure GEMM) ----------
// 256 thr = 4 waves x 32 rows = 128 rows/block. Histogram removed (round-5: CSR build
// is now a global-atomic-free LDS counting sort in k_bin*/k_scat1/k_sortf).
__global__ void __launch_bounds__(256, 2)
k_qkvm(const float* __restrict__ x,
       const half8* __restrict__ whi, const half8* __restrict__ wlo,
       const float* __restrict__ w127,
       const float* __restrict__ bq, const float* __restrict__ bk,
       const float* __restrict__ bv,
       float* __restrict__ qn, float* __restrict__ kvout, int N) {
    __shared__ half8 bsh[4096];       // 64 KB: [0..2048) hi, [2048..4096) lo

    int tid = threadIdx.x;
    int wv = tid >> 6;                // wave 0..3
    int l = tid & 63;
    int r = l & 15;                   // A-row / out-col lane index
    int g = l >> 4;                   // k-group / out-row group
    int rowbase = blockIdx.x * 128 + wv * 32;
    const float4* x4 = (const float4*)x;

    // ---- issue kind-0 B staging first (latency overlaps x processing) ----
    {
        const half8* sH = whi + wv * 512;
        const half8* sL = wlo + wv * 512;
#pragma unroll
        for (int i = 0; i < 8; i++) {
            gl_lds16(sH + i * 64 + l, bsh + wv * 512 + i * 64);
            gl_lds16(sL + i * 64 + l, bsh + 2048 + wv * 512 + i * 64);
        }
    }

    // ---- load x for 2 row-tiles, build hi/lo frags, fold normalization ----
    half8 hiA[2][4], loA[2][4];
    float rnj[2][4], tcj[2][4];
#pragma unroll
    for (int t = 0; t < 2; t++) {
        int row = min(rowbase + t * 16 + r, N - 1);
        float ssum = 0.f, tl = 0.f;
#pragma unroll
        for (int ks = 0; ks < 4; ks++) {
            float4 a = x4[(size_t)row * 32 + ks * 8 + g * 2];
            float4 bb = x4[(size_t)row * 32 + ks * 8 + g * 2 + 1];
            float xv[8] = {a.x, a.y, a.z, a.w, bb.x, bb.y, bb.z, bb.w};
#pragma unroll
            for (int j = 0; j < 8; j++) {
                _Float16 hh = (_Float16)xv[j];
                hiA[t][ks][j] = hh;
                loA[t][ks][j] = (_Float16)((xv[j] - (float)hh) * 4096.0f);
                ssum += xv[j] * xv[j];
            }
            if (ks == 3 && g == 3) { tl = xv[7]; ssum -= xv[7] * xv[7]; }
        }
        ssum += __shfl_xor(ssum, 16);
        ssum += __shfl_xor(ssum, 32);
        float rn = 1.f / fmaxf(sqrtf(ssum), EPSF);
        float tla = __shfl(tl, 48 + r);        // x127 of row (t, r)
        float tc = tla * (1.f - rn);
#pragma unroll
        for (int j = 0; j < 4; j++) {
            rnj[t][j] = __shfl(rn, g * 4 + j);
            tcj[t][j] = __shfl(tc, g * 4 + j);
        }
    }

    asm volatile("s_waitcnt vmcnt(0)" ::: "memory");
    __syncthreads();                  // kind-0 B resident in LDS

    const float* const bks[3] = {bq, bk, bv};
    bool lane15 = (r == 15);
    const f32x4 zz = {0.f, 0.f, 0.f, 0.f};
    int dsbase = g * 128 + r;         // half8-slot base for this lane

    for (int kind = 0; kind < 3; kind++) {
        float wcA[2][4], bbA[2][4];
#pragma unroll
        for (int h = 0; h < 2; h++)
#pragma unroll
            for (int ct = 0; ct < 4; ct++) {
                int col = (h * 4 + ct) * 16 + r;
                wcA[h][ct] = w127[kind * 128 + col];
                bbA[h][ct] = bks[kind][col];
            }

#pragma unroll
        for (int h = 0; h < 2; h++) {
            f32x4 aM[2][4], aX[2][4];
#pragma unroll
            for (int t = 0; t < 2; t++)
#pragma unroll
                for (int ct = 0; ct < 4; ct++) { aM[t][ct] = zz; aX[t][ct] = zz; }

#pragma unroll
            for (int ks = 0; ks < 4; ks++) {
                half8 hB[4], lB[4];
#pragma unroll
                for (int ct = 0; ct < 4; ct++) {
                    int bi = dsbase + ks * 512 + (h * 4 + ct) * 16;
                    hB[ct] = bsh[bi];
                    lB[ct] = bsh[2048 + bi];
                }
#pragma unroll
                for (int ct = 0; ct < 4; ct++) {
                    aM[0][ct] = __builtin_amdgcn_mfma_f32_16x16x32_f16(hiA[0][ks], hB[ct], aM[0][ct], 0, 0, 0);
                    aM[1][ct] = __builtin_amdgcn_mfma_f32_16x16x32_f16(hiA[1][ks], hB[ct], aM[1][ct], 0, 0, 0);
                    aX[0][ct] = __builtin_amdgcn_mfma_f32_16x16x32_f16(hiA[0][ks], lB[ct], aX[0][ct], 0, 0, 0);
                    aX[0][ct] = __builtin_amdgcn_mfma_f32_16x16x32_f16(loA[0][ks], hB[ct], aX[0][ct], 0, 0, 0);
                    aX[1][ct] = __builtin_amdgcn_mfma_f32_16x16x32_f16(hiA[1][ks], lB[ct], aX[1][ct], 0, 0, 0);
                    aX[1][ct] = __builtin_amdgcn_mfma_f32_16x16x32_f16(loA[1][ks], hB[ct], aX[1][ct], 0, 0, 0);
                }
            }

            // epilogue for head h: combine, norm-correct, q/k head-normalize, store
#pragma unroll
            for (int t = 0; t < 2; t++) {
                float cv[4][4];       // [ct][j]
#pragma unroll
                for (int ct = 0; ct < 4; ct++)
#pragma unroll
                    for (int j = 0; j < 4; j++) {
                        float acc = aM[t][ct][j] + aX[t][ct][j] * (1.0f / 4096.0f);
                        cv[ct][j] = fmaf(rnj[t][j], acc, fmaf(tcj[t][j], wcA[h][ct], bbA[h][ct]));
                    }
                if (kind < 2) {
#pragma unroll
                    for (int j = 0; j < 4; j++) {
                        float ss = 0.f;
#pragma unroll
                        for (int ct = 0; ct < 4; ct++) {
                            float c = cv[ct][j];
                            ss += (ct == 3 && lane15) ? 0.f : c * c;
                        }
                        ss += __shfl_xor(ss, 1);
                        ss += __shfl_xor(ss, 2);
                        ss += __shfl_xor(ss, 4);
                        ss += __shfl_xor(ss, 8);
                        float rh = 1.f / fmaxf(sqrtf(ss), EPSF);
#pragma unroll
                        for (int ct = 0; ct < 4; ct++) {
                            bool ist = (ct == 3) && lane15;
                            if (!ist) cv[ct][j] *= rh;
                            if (kind == 0) {
                                if (ist) cv[ct][j] = -cv[ct][j];
                                cv[ct][j] *= INV_SQRT128;
                            }
                        }
                    }
                }
#pragma unroll
                for (int j = 0; j < 4; j++) {
                    int row = rowbase + t * 16 + g * 4 + j;
                    if (row < N) {
                        float* dst = (kind == 0)
                            ? (qn + (size_t)row * 128)
                            : (kvout + (size_t)row * 256 + (kind == 2 ? 128 : 0));
#pragma unroll
                        for (int ct = 0; ct < 4; ct++)
                            dst[(h * 4 + ct) * 16 + r] = cv[ct][j];
                    }
                }
            }
        }

        if (kind < 2) {               // restage B for next kind
            __syncthreads();
            const half8* sH = whi + (kind + 1) * 2048 + wv * 512;
            const half8* sL = wlo + (kind + 1) * 2048 + wv * 512;
#pragma unroll
            for (int i = 0; i < 8; i++) {
                gl_lds16(sH + i * 64 + l, bsh + wv * 512 + i * 64);
                gl_lds16(sL + i * 64 + l, bsh + 2048 + wv * 512 + i * 64);
            }
            asm volatile("s_waitcnt vmcnt(0)" ::: "memory");
            __syncthreads();
        }
    }
}

// ---------------- CSR build via 2-pass LDS counting sort (NO global atomics) ----------
// Pass 1a: per-(block, coarse-bin) counts. bin = row>>9 (<=256 bins for N<=131072).
__global__ void k_bin1(const int* __restrict__ ei, int* __restrict__ bcnt,
                       int E, int chunk) {
    __shared__ int h[256];
    int t = threadIdx.x, b = blockIdx.x;
    h[t] = 0;
    __syncthreads();
    int s = b * chunk, e1 = min(s + chunk, E);
    for (int e = s + t; e < e1; e += 256) atomicAdd(&h[ei[e] >> 9], 1);
    __syncthreads();
    bcnt[b * 256 + t] = h[t];
}

// Pass 1b: per-bin exclusive scan over the 256 pass-1 blocks (in-place) + bin totals.
__global__ void k_bin2(int* __restrict__ bcnt, int* __restrict__ bintot) {
    __shared__ int sd[256];
    int b = blockIdx.x, t = threadIdx.x;
    int v = bcnt[t * 256 + b];
    sd[t] = v;
    __syncthreads();
    for (int off = 1; off < 256; off <<= 1) {
        int val = sd[t];
        int add = (t >= off) ? sd[t - off] : 0;
        __syncthreads();
        sd[t] = val + add;
        __syncthreads();
    }
    bcnt[t * 256 + b] = sd[t] - v;    // exclusive
    if (t == 255) bintot[b] = sd[255];
}

// Pass 1c: exclusive scan over 256 bin totals -> binoff; also offs[N]=E.
__global__ void k_bin3(const int* __restrict__ bintot, int* __restrict__ binoff,
                       int* __restrict__ offs, int N, int E) {
    __shared__ int sd[256];
    int t = threadIdx.x;
    int v = bintot[t];
    sd[t] = v;
    __syncthreads();
    for (int off = 1; off < 256; off <<= 1) {
        int val = sd[t];
        int add = (t >= off) ? sd[t - off] : 0;
        __syncthreads();
        sd[t] = val + add;
        __syncthreads();
    }
    binoff[t] = sd[t] - v;
    if (t == 255) {
        binoff[256] = sd[255];
        offs[N] = E;
    }
}

// Pass 1d: scatter edges into bin-grouped order, packed (row&511)<<17 | col (N < 2^17).
__global__ void k_scat1(const int* __restrict__ ei, const int* __restrict__ bcnt,
                        const int* __restrict__ binoff, int* __restrict__ packed,
                        int E, int chunk) {
    __shared__ int cur[256];
    int t = threadIdx.x, b = blockIdx.x;
    cur[t] = binoff[t] + bcnt[b * 256 + t];
    __syncthreads();
    int s = b * chunk, e1 = min(s + chunk, E);
    for (int e = s + t; e < e1; e += 256) {
        int r = ei[e];
        int c = ei[E + e];
        int p = atomicAdd(&cur[r >> 9], 1);
        packed[p] = ((r & 511) << 17) | c;
    }
}

// Pass 2: per-bin fine sort. Stages segment in LDS (packed aliases ccol -> must stage
// fully before writing). Emits offs[] exactly and ccol in CSR order.
__global__ void __launch_bounds__(256)
k_sortf(const int* __restrict__ packed, const int* __restrict__ binoff,
        int* __restrict__ ccol, int* __restrict__ offs, int N) {
    __shared__ int seg[6656];         // bin size ~5120 +- 72; 6656 = +21 sigma
    __shared__ int h[512];
    __shared__ int sc[256];
    int b = blockIdx.x, t = threadIdx.x;
    int s = binoff[b], e1 = binoff[b + 1];
    int cnt = min(e1 - s, 6656);
    for (int i = t; i < cnt; i += 256) seg[i] = packed[s + i];
    h[t] = 0;
    h[t + 256] = 0;
    __syncthreads();
    for (int i = t; i < cnt; i += 256) atomicAdd(&h[seg[i] >> 17], 1);
    __syncthreads();
    int v0 = h[2 * t], v1 = h[2 * t + 1];
    int pair = v0 + v1;
    sc[t] = pair;
    __syncthreads();
    for (int off = 1; off < 256; off <<= 1) {
        int val = sc[t];
        int add = (t >= off) ? sc[t - off] : 0;
        __syncthreads();
        sc[t] = val + add;
        __syncthreads();
    }
    int pexcl = sc[t] - pair;
    __syncthreads();
    h[2 * t] = pexcl;
    h[2 * t + 1] = pexcl + v0;
    // offs for this bin's rows (each thread reads only its own h entries)
    int rowbase = b << 9;
    if (rowbase + 2 * t < N) offs[rowbase + 2 * t] = s + h[2 * t];
    if (rowbase + 2 * t + 1 < N) offs[rowbase + 2 * t + 1] = s + h[2 * t + 1];
    __syncthreads();
    // scatter (h doubles as cursor array)
    for (int i = t; i < cnt; i += 256) {
        int pk = seg[i];
        int p = atomicAdd(&h[pk >> 17], 1);
        ccol[s + p] = pk & 0x1FFFF;
    }
}

// ---------------- fused edge pass: scores + exp + aggregate (unnormalized) ----------------
__global__ void k_edge(const float* __restrict__ qn, const float* __restrict__ kv,
                       const int* __restrict__ offs, const int* __restrict__ ccol,
                       float* __restrict__ U, double* __restrict__ psum, int N) {
    int g = threadIdx.x >> 5;            // 8 groups of 32 lanes
    int l = threadIdx.x & 31;
    int head = l >> 4;
    int n = blockIdx.x * 8 + g;
    double esum = 0.0;
    if (n < N) {
        float4 q4 = ((const float4*)qn)[(size_t)n * 32 + l];
        int s0 = offs[n], s1 = offs[n + 1];
        float4 acc = {0.f, 0.f, 0.f, 0.f};
        const float4* kv4 = (const float4*)kv;
        int i = s0;
        for (; i + 4 <= s1; i += 4) {
            int c0 = ccol[i];
            int c1 = ccol[i + 1];
            int c2 = ccol[i + 2];
            int c3 = ccol[i + 3];
            float4 ka = kv4[(size_t)c0 * 64 + l];
            float4 va = kv4[(size_t)c0 * 64 + 32 + l];
            float4 kb = kv4[(size_t)c1 * 64 + l];
            float4 vb = kv4[(size_t)c1 * 64 + 32 + l];
            float4 kc = kv4[(size_t)c2 * 64 + l];
            float4 vc = kv4[(size_t)c2 * 64 + 32 + l];
            float4 kd = kv4[(size_t)c3 * 64 + l];
            float4 vd = kv4[(size_t)c3 * 64 + 32 + l];
            float p0 = q4.x * ka.x;
            p0 = fmaf(q4.y, ka.y, p0); p0 = fmaf(q4.z, ka.z, p0); p0 = fmaf(q4.w, ka.w, p0);
            float p1 = q4.x * kb.x;
            p1 = fmaf(q4.y, kb.y, p1); p1 = fmaf(q4.z, kb.z, p1); p1 = fmaf(q4.w, kb.w, p1);
            float p2 = q4.x * kc.x;
            p2 = fmaf(q4.y, kc.y, p2); p2 = fmaf(q4.z, kc.z, p2); p2 = fmaf(q4.w, kc.w, p2);
            float p3 = q4.x * kd.x;
            p3 = fmaf(q4.y, kd.y, p3); p3 = fmaf(q4.z, kd.z, p3); p3 = fmaf(q4.w, kd.w, p3);
            p0 += __shfl_xor(p0, 1); p1 += __shfl_xor(p1, 1);
            p2 += __shfl_xor(p2, 1); p3 += __shfl_xor(p3, 1);
            p0 += __shfl_xor(p0, 2); p1 += __shfl_xor(p1, 2);
            p2 += __shfl_xor(p2, 2); p3 += __shfl_xor(p3, 2);
            p0 += __shfl_xor(p0, 4); p1 += __shfl_xor(p1, 4);
            p2 += __shfl_xor(p2, 4); p3 += __shfl_xor(p3, 4);
            p0 += __shfl_xor(p0, 8); p1 += __shfl_xor(p1, 8);
            p2 += __shfl_xor(p2, 8); p3 += __shfl_xor(p3, 8);
            float e0 = expf(p0);
            float e1 = expf(p1);
            float e2 = expf(p2);
            float e3 = expf(p3);
            acc.x = fmaf(va.x, e0, acc.x); acc.y = fmaf(va.y, e0, acc.y);
            acc.z = fmaf(va.z, e0, acc.z); acc.w = fmaf(va.w, e0, acc.w);
            acc.x = fmaf(vb.x, e1, acc.x); acc.y = fmaf(vb.y, e1, acc.y);
            acc.z = fmaf(vb.z, e1, acc.z); acc.w = fmaf(vb.w, e1, acc.w);
            acc.x = fmaf(vc.x, e2, acc.x); acc.y = fmaf(vc.y, e2, acc.y);
            acc.z = fmaf(vc.z, e2, acc.z); acc.w = fmaf(vc.w, e2, acc.w);
            acc.x = fmaf(vd.x, e3, acc.x); acc.y = fmaf(vd.y, e3, acc.y);
            acc.z = fmaf(vd.z, e3, acc.z); acc.w = fmaf(vd.w, e3, acc.w);
            esum += (double)((e0 + e1) + (e2 + e3));
        }
        for (; i < s1; i++) {
            int c = ccol[i];
            float4 k4 = kv4[(size_t)c * 64 + l];
            float4 v4 = kv4[(size_t)c * 64 + 32 + l];
            float p = q4.x * k4.x;
            p = fmaf(q4.y, k4.y, p); p = fmaf(q4.z, k4.z, p); p = fmaf(q4.w, k4.w, p);
            p += __shfl_xor(p, 1);
            p += __shfl_xor(p, 2);
            p += __shfl_xor(p, 4);
            p += __shfl_xor(p, 8);
            float e = expf(p);
            acc.x = fmaf(v4.x, e, acc.x); acc.y = fmaf(v4.y, e, acc.y);
            acc.z = fmaf(v4.z, e, acc.z); acc.w = fmaf(v4.w, e, acc.w);
            esum += (double)e;
        }
        ((float4*)U)[(size_t)n * 32 + l] = acc;
    }
    __shared__ double sd[2][8];
    if ((l & 15) == 0) sd[head][g] = esum;
    __syncthreads();
    if (threadIdx.x < 2) {
        double s = 0.0;
        for (int i2 = 0; i2 < 8; i2++) s += sd[threadIdx.x][i2];
        psum[(size_t)blockIdx.x * 2 + threadIdx.x] = s;
    }
}

// deterministic reduce of per-block partials -> sumf[2] (double)
__global__ void k_sum2(const double* __restrict__ psum, double* __restrict__ sumf, int P) {
    double s0 = 0.0, s1 = 0.0;
    for (int i = threadIdx.x; i < P; i += blockDim.x) {
        s0 += psum[2 * i];
        s1 += psum[2 * i + 1];
    }
    for (int off = 32; off; off >>= 1) {
        s0 += __shfl_xor(s0, off);
        s1 += __shfl_xor(s1, off);
    }
    __shared__ double sd[2][4];
    int w = threadIdx.x >> 6;
    if ((threadIdx.x & 63) == 0) { sd[0][w] = s0; sd[1][w] = s1; }
    __syncthreads();
    if (threadIdx.x == 0) {
        for (int i = 1; i < 4; i++) { s0 += sd[0][i]; s1 += sd[1][i]; }
        sumf[0] = s0;
        sumf[1] = s1;
    }
}

// ---------------- cr_initial (from x) + rows 0-3 of out + scale factor ----------------
__global__ void k_crout4(const float* __restrict__ x, const float* __restrict__ U,
                         const float* __restrict__ Wo, const float* __restrict__ bo,
                         const double* __restrict__ sumf, float* __restrict__ scalef) {
    __shared__ float xs[4 * 128];
    __shared__ float o4[4 * 64];
    __shared__ double crin_sh;
    int tid = threadIdx.x;  // 256
    xs[tid] = U[tid];
    xs[tid + 256] = U[tid + 256];
    if (tid < 64) {         // wave 0: cross-ratio of raw x rows 0..3
        int l = tid;
        const int pa[4] = {0, 1, 0, 1};
        const int pb[4] = {2, 3, 3, 2};
        double inner[4];
        for (int p = 0; p < 4; p++) {
            const float* a = x + pa[p] * 128;
            const float* b = x + pb[p] * 128;
            double s = (double)a[l] * (double)b[l];
            double t = (double)a[l + 64] * (double)b[l + 64];
            s += (l == 63) ? -t : t;
            for (int off = 32; off; off >>= 1) s += __shfl_xor(s, off);
            inner[p] = s;
        }
        if (l == 0) {
            double num = inner[0] * inner[1];
            double den = inner[2] * inner[3];
            if (fabs(den) < 1e-9) den = 1e-9;
            crin_sh = num / den;
        }
    }
    __syncthreads();
    int w = tid >> 6, o = tid & 63;
    float si0 = (float)(1.0 / sumf[0]);
    float si1 = (float)(1.0 / sumf[1]);
    const float* xr = xs + w * 128;
    const float* wr = Wo + (size_t)o * 128;
    float d0 = 0.f, d1 = 0.f;
    for (int j = 0; j < 64; j++) d0 = fmaf(xr[j], wr[j], d0);
    for (int j = 64; j < 128; j++) d1 = fmaf(xr[j], wr[j], d1);
    o4[w * 64 + o] = d0 * si0 + d1 * si1 + bo[o];
    __syncthreads();
    if (tid < 64) {
        int l = tid;
        const int pa[4] = {0, 1, 0, 1};
        const int pb[4] = {2, 3, 3, 2};
        double inner[4];
        for (int p = 0; p < 4; p++) {
            double t = (double)o4[pa[p] * 64 + l] * (double)o4[pb[p] * 64 + l];
            if (l == 63) t = -t;
            for (int off = 32; off; off >>= 1) t += __shfl_xor(t, off);
            inner[p] = t;
        }
        if (l == 0) {
            double num = inner[0] * inner[1];
            double den = inner[2] * inner[3];
            if (fabs(den) < 1e-9) den = 1e-9;
            double crc = num / den;
            if (fabs(crc) < 1e-9) crc = 1e-9;
            double ratio = crin_sh / crc;
            scalef[0] = (float)pow(fabs(ratio), 0.25);
        }
    }
}

// ---------------- final GEMM via split-fp16 MFMA: out = ((U/sumf)@Wo.T + bo)*scalef ----
__global__ void __launch_bounds__(256, 2)
k_outm(const float* __restrict__ U, const half8* __restrict__ wohi,
       const half8* __restrict__ wolo, const float* __restrict__ bo,
       const double* __restrict__ sumf, const float* __restrict__ scalef,
       float* __restrict__ out, int N) {
    __shared__ half8 bsh[2048];       // 32 KB: [0..1024) hi, [1024..2048) lo
    int tid = threadIdx.x;
    int wv = tid >> 6;                // wave 0..3
    int l = tid & 63;
    int r = l & 15;
    int g = l >> 4;
    int rowbase = blockIdx.x * 128 + wv * 32;

    {   // stage Wo frags
        const half8* sH = wohi + wv * 256;
        const half8* sL = wolo + wv * 256;
#pragma unroll
        for (int i = 0; i < 4; i++) {
            gl_lds16(sH + i * 64 + l, bsh + wv * 256 + i * 64);
            gl_lds16(sL + i * 64 + l, bsh + 1024 + wv * 256 + i * 64);
        }
    }

    float si0 = (float)(1.0 / sumf[0]);
    float si1 = (float)(1.0 / sumf[1]);
    const float4* U4 = (const float4*)U;
    half8 hiA[2][4], loA[2][4];
#pragma unroll
    for (int t = 0; t < 2; t++) {
        int row = min(rowbase + t * 16 + r, N - 1);
#pragma unroll
        for (int ks = 0; ks < 4; ks++) {
            float si = (ks < 2) ? si0 : si1;
            float4 a = U4[(size_t)row * 32 + ks * 8 + g * 2];
            float4 b = U4[(size_t)row * 32 + ks * 8 + g * 2 + 1];
            float xv[8] = {a.x, a.y, a.z, a.w, b.x, b.y, b.z, b.w};
#pragma unroll
            for (int j = 0; j < 8; j++) {
                float v = xv[j] * si;
                _Float16 hh = (_Float16)v;
                hiA[t][ks][j] = hh;
                loA[t][ks][j] = (_Float16)((v - (float)hh) * 4096.0f);
            }
        }
    }

    asm volatile("s_waitcnt vmcnt(0)" ::: "memory");
    __syncthreads();

    const f32x4 zz = {0.f, 0.f, 0.f, 0.f};
    f32x4 aM[2][4], aX[2][4];
#pragma unroll
    for (int t = 0; t < 2; t++)
#pragma unroll
        for (int ct = 0; ct < 4; ct++) { aM[t][ct] = zz; aX[t][ct] = zz; }

#pragma unroll
    for (int ks = 0; ks < 4; ks++) {
        half8 hB[4], lB[4];
#pragma unroll
        for (int ct = 0; ct < 4; ct++) {
            int bi = ks * 256 + g * 64 + ct * 16 + r;
            hB[ct] = bsh[bi];
            lB[ct] = bsh[1024 + bi];
        }
#pragma unroll
        for (int ct = 0; ct < 4; ct++) {
            aM[0][ct] = __builtin_amdgcn_mfma_f32_16x16x32_f16(hiA[0][ks], hB[ct], aM[0][ct], 0, 0, 0);
            aM[1][ct] = __builtin_amdgcn_mfma_f32_16x16x32_f16(hiA[1][ks], hB[ct], aM[1][ct], 0, 0, 0);
            aX[0][ct] = __builtin_amdgcn_mfma_f32_16x16x32_f16(hiA[0][ks], lB[ct], aX[0][ct], 0, 0, 0);
            aX[0][ct] = __builtin_amdgcn_mfma_f32_16x16x32_f16(loA[0][ks], hB[ct], aX[0][ct], 0, 0, 0);
            aX[1][ct] = __builtin_amdgcn_mfma_f32_16x16x32_f16(hiA[1][ks], lB[ct], aX[1][ct], 0, 0, 0);
            aX[1][ct] = __builtin_amdgcn_mfma_f32_16x16x32_f16(loA[1][ks], hB[ct], aX[1][ct], 0, 0, 0);
        }
    }

    float sf = scalef[0];
#pragma unroll
    for (int t = 0; t < 2; t++)
#pragma unroll
        for (int ct = 0; ct < 4; ct++) {
            float bb = bo[ct * 16 + r];
#pragma unroll
            for (int j = 0; j < 4; j++) {
                int row = rowbase + t * 16 + g * 4 + j;
                if (row < N) {
                    float c = (aM[t][ct][j] + aX[t][ct][j] * (1.0f / 4096.0f) + bb) * sf;
                    out[(size_t)row * 64 + ct * 16 + r] = c;
                }
            }
        }
}

extern "C" void kernel_launch(void* const* d_in, const int* in_sizes, int n_in,
                              void* d_out, int out_size, void* d_ws, size_t ws_size,
                              hipStream_t stream) {
    const float* x  = (const float*)d_in[0];
    const int*   ei = (const int*)d_in[1];
    const float* Wq = (const float*)d_in[2];
    const float* bq = (const float*)d_in[3];
    const float* Wk = (const float*)d_in[4];
    const float* bk = (const float*)d_in[5];
    const float* Wv = (const float*)d_in[6];
    const float* bv = (const float*)d_in[7];
    const float* Wo = (const float*)d_in[8];
    const float* bo = (const float*)d_in[9];
    float* out = (float*)d_out;

    const int N = in_sizes[0] / 128;   // 100000
    const int E = in_sizes[1] / 2;     // 1000000
    const size_t NR = (size_t)N * 128;
    const int NGB = (N + 127) / 128;   // 782 GEMM blocks
    const int GB = (N + 7) / 8;        // 12500 edge-kernel blocks
    const int NBK1 = 256;              // pass-1 sort blocks
    const int chunk = (E + NBK1 - 1) / NBK1;
    const int NBINS = (N + 511) >> 9;  // 196 coarse bins (row>>9)

    float* qn = (float*)d_ws;          // N*128 ; reused as U after k_edge
    float* kv = qn + NR;               // N*256 (k|v interleaved per node)
    int* offs = (int*)(kv + NR * 2);           // N+1
    int* ccol = offs + N + 2;                  // E (also packed tmp for the sort)
    int* bcnt = ccol + E;                      // 256*256
    int* bintot = bcnt + 256 * 256;            // 256
    int* binoff = bintot + 256;                // 257
    uintptr_t pd = ((uintptr_t)(binoff + 257 + 1) + 7) & ~(uintptr_t)7;
    double* psum = (double*)pd;                // GB*2 partial expsums
    double* sumf = psum + (size_t)GB * 2;      // 2
    float* scalef = (float*)(sumf + 2);        // 1

    // packed Wq/Wk/Wv frags alias ccol (dead until k_scat1, consumed by k_qkvm first)
    uintptr_t pw = ((uintptr_t)ccol + 15) & ~(uintptr_t)15;
    half8* whi = (half8*)pw;                   // 6144 * 16B
    half8* wlo = whi + 6144;                   // 6144 * 16B
    float* w127 = (float*)(wlo + 6144);        // 3*128 floats

    // packed Wo frags alias bcnt (dead after k_scat1; k_wpack2 runs after it)
    uintptr_t pw2 = ((uintptr_t)bcnt + 15) & ~(uintptr_t)15;
    half8* wohi = (half8*)pw2;                 // 1024 * 16B
    half8* wolo = wohi + 1024;                 // 1024 * 16B

    float* U = qn;  // aggregation output aliases q (per-n read-then-write)

    k_wpack<<<24, 256, 0, stream>>>(Wq, Wk, Wv, whi, wlo, w127);
    k_qkvm<<<NGB, 256, 0, stream>>>(x, whi, wlo, w127, bq, bk, bv, qn, kv, N);
    k_bin1<<<NBK1, 256, 0, stream>>>(ei, bcnt, E, chunk);
    k_bin2<<<256, 256, 0, stream>>>(bcnt, bintot);
    k_bin3<<<1, 256, 0, stream>>>(bintot, binoff, offs, N, E);
    k_scat1<<<NBK1, 256, 0, stream>>>(ei, bcnt, binoff, ccol, E, chunk);
    k_wpack2<<<4, 256, 0, stream>>>(Wo, wohi, wolo);   // bcnt space now dead
    k_sortf<<<NBINS, 256, 0, stream>>>(ccol, binoff, ccol, offs, N);
    k_edge<<<GB, 256, 0, stream>>>(qn, kv, offs, ccol, U, psum, N);
    k_sum2<<<1, 256, 0, stream>>>(psum, sumf, GB);
    k_crout4<<<1, 256, 0, stream>>>(x, U, Wo, bo, sumf, scalef);
    k_outm<<<NGB, 256, 0, stream>>>(U, wohi, wolo, bo, sumf, scalef, out, N);
}